// Round 1
// baseline (829.596 us; speedup 1.0000x reference)
//
#include <hip/hip_runtime.h>
#include <math.h>

#define BB 32
#define LL 512
#define DM 128
#define DI 256
#define DSN 16
#define NMK 4

__device__ __forceinline__ float silu_f(float x){ return x / (1.f + expf(-x)); }

// ---------------- 1. per-batch normalization ----------------
__global__ void norm_kernel(const float* __restrict__ x_enc,
                            float* __restrict__ xn, float* __restrict__ stats){
  __shared__ float xs[LL];
  __shared__ float red[256];
  int b = blockIdx.x, t = threadIdx.x;
  xs[t]       = x_enc[b*LL + t];
  xs[t + 256] = x_enc[b*LL + t + 256];
  __syncthreads();
  red[t] = xs[t] + xs[t + 256];
  __syncthreads();
  for (int s = 128; s; s >>= 1){ if (t < s) red[t] += red[t + s]; __syncthreads(); }
  float mean = red[0] / (float)LL;
  __syncthreads();                      // protect red[0] before reuse
  float xc0 = xs[t] - mean, xc1 = xs[t + 256] - mean;
  red[t] = xc0*xc0 + xc1*xc1;
  __syncthreads();
  for (int s = 128; s; s >>= 1){ if (t < s) red[t] += red[t + s]; __syncthreads(); }
  float var = red[0] / (float)LL;
  float sd = sqrtf(var + 1e-5f);
  xn[b*LL + t]       = xc0 / sd;
  xn[b*LL + t + 256] = xc1 / sd;
  if (t == 0){ stats[b] = mean; stats[BB + b] = sd; }
}

// ---------------- 2. token conv + temporal + positional embedding ----------------
__global__ void embed_kernel(const float* __restrict__ xn, const float* __restrict__ xmark,
                             const float* __restrict__ tok_w, const float* __restrict__ temp_w,
                             float* __restrict__ xbuf){
  int row = blockIdx.x;          // b*LL + l
  int o = threadIdx.x;           // 0..127
  int b = row >> 9, l = row & 511;
  float xm1 = xn[b*LL + ((l == 0) ? (LL - 1) : (l - 1))];
  float x0  = xn[row];
  float xp1 = xn[b*LL + ((l == LL - 1) ? 0 : (l + 1))];
  float v = xm1 * tok_w[o*3 + 0] + x0 * tok_w[o*3 + 1] + xp1 * tok_w[o*3 + 2];
  #pragma unroll
  for (int m = 0; m < NMK; ++m) v += xmark[row*NMK + m] * temp_w[m*DM + o];
  int i = o >> 1;
  float ang = (float)l * expf((float)(2*i) * -0.07195578415606394f); // -ln(10000)/128
  v += (o & 1) ? cosf(ang) : sinf(ang);
  xbuf[row*DM + o] = v;
}

// ---------------- 3/7. tiled f32 GEMM, 64x64 tile, 256 thr ----------------
// MODE 0: out0[row*N+col] = acc
// MODE 1: (in_proj) col<256 -> xi_raw, col>=256 -> silu -> zbuf
template<int MODE>
__global__ __launch_bounds__(256) void gemm64_kernel(const float* __restrict__ A,
    const float* __restrict__ W, float* __restrict__ out0, float* __restrict__ out1,
    int M, int N, int K){
  __shared__ float AsT[32][68];   // [k][row], row-stride 272B (16B aligned)
  __shared__ float Bs[32][64];    // [k][col]
  int tid = threadIdx.x;
  int tx = tid & 15, ty = tid >> 4;
  int rowBase = blockIdx.x * 64, colBase = blockIdx.y * 64;
  float acc[4][4] = {};
  for (int kc = 0; kc < K; kc += 32){
    #pragma unroll
    for (int i = 0; i < 8; ++i){
      int idx = tid + i*256;
      int r = idx >> 5, k = idx & 31;
      AsT[k][r] = A[(size_t)(rowBase + r)*K + kc + k];
    }
    #pragma unroll
    for (int i = 0; i < 8; ++i){
      int idx = tid + i*256;
      int k = idx >> 6, c = idx & 63;
      Bs[k][c] = W[(size_t)(kc + k)*N + colBase + c];
    }
    __syncthreads();
    #pragma unroll
    for (int k = 0; k < 32; ++k){
      float4 a  = *(const float4*)&AsT[k][ty*4];
      float4 bv = *(const float4*)&Bs[k][tx*4];
      float av[4] = {a.x, a.y, a.z, a.w};
      float bb[4] = {bv.x, bv.y, bv.z, bv.w};
      #pragma unroll
      for (int ii = 0; ii < 4; ++ii)
        #pragma unroll
        for (int jj = 0; jj < 4; ++jj) acc[ii][jj] += av[ii]*bb[jj];
    }
    __syncthreads();
  }
  #pragma unroll
  for (int ii = 0; ii < 4; ++ii){
    int row = rowBase + ty*4 + ii;
    #pragma unroll
    for (int jj = 0; jj < 4; ++jj){
      int col = colBase + tx*4 + jj;
      float v = acc[ii][jj];
      if (MODE == 0){
        out0[(size_t)row*N + col] = v;
      } else {
        if (col < DI) out0[(size_t)row*DI + col] = v;
        else          out1[(size_t)row*DI + col - DI] = silu_f(v);
      }
    }
  }
}

// ---------------- 4. depthwise causal conv + silu ----------------
__global__ void conv_kernel(const float* __restrict__ xi_raw, const float* __restrict__ conv_w,
                            const float* __restrict__ conv_b, float* __restrict__ xi2){
  int row = blockIdx.x, d = threadIdx.x;
  int l = row & 511;
  float acc = conv_b[d];
  #pragma unroll
  for (int k = 0; k < 4; ++k){
    int t = l + k - 3;
    if (t >= 0) acc += xi_raw[(size_t)(row + k - 3)*DI + d] * conv_w[d*4 + k];
  }
  xi2[(size_t)row*DI + d] = silu_f(acc);
}

// ---------------- 5. dbl = xi2 @ x_proj_w  (M=16384, N=40, K=256) ----------------
__global__ __launch_bounds__(256) void dbl_kernel(const float* __restrict__ xi2,
    const float* __restrict__ xpw, float* __restrict__ dbl){
  __shared__ float Xs[64][65];    // [k][row]
  __shared__ float Ws[64][48];    // [k][col], padded 40->48
  int t = threadIdx.x;
  int r = t >> 2, g = t & 3;      // row 0..63, colgroup 0..3 (12 cols each)
  int rowBase = blockIdx.x * 64;
  float acc[12] = {};
  for (int kc = 0; kc < DI; kc += 64){
    #pragma unroll
    for (int i = 0; i < 16; ++i){
      int idx = t + i*256;
      int rr = idx >> 6, k = idx & 63;
      Xs[k][rr] = xi2[(size_t)(rowBase + rr)*DI + kc + k];
    }
    #pragma unroll
    for (int i = 0; i < 12; ++i){
      int idx = t + i*256;
      int k = idx / 48, j = idx % 48;
      Ws[k][j] = (j < 40) ? xpw[(kc + k)*40 + j] : 0.f;
    }
    __syncthreads();
    for (int k = 0; k < 64; ++k){
      float a = Xs[k][r];
      const float4* wr = (const float4*)&Ws[k][g*12];
      float4 w0 = wr[0], w1 = wr[1], w2 = wr[2];
      acc[0]  += a*w0.x; acc[1]  += a*w0.y; acc[2]  += a*w0.z; acc[3]  += a*w0.w;
      acc[4]  += a*w1.x; acc[5]  += a*w1.y; acc[6]  += a*w1.z; acc[7]  += a*w1.w;
      acc[8]  += a*w2.x; acc[9]  += a*w2.y; acc[10] += a*w2.z; acc[11] += a*w2.w;
    }
    __syncthreads();
  }
  int row = rowBase + r;
  #pragma unroll
  for (int jj = 0; jj < 12; ++jj){
    int j = g*12 + jj;
    if (j < 40) dbl[(size_t)row*40 + j] = acc[jj];
  }
}

// ---------------- 6. fused selective scan ----------------
// thread = d channel; block = batch b. Computes dt (softplus), dA, dBu, recurrence,
// y = (scan + D*xi)*silu(z) — silu(z) precomputed in zbuf.
__global__ __launch_bounds__(256) void scan_kernel(const float* __restrict__ xi2,
    const float* __restrict__ zbuf, const float* __restrict__ dbl,
    const float* __restrict__ A_log, const float* __restrict__ dt_w,
    const float* __restrict__ dt_b, const float* __restrict__ Dp,
    float* __restrict__ ybuf){
  int b = blockIdx.x, d = threadIdx.x;
  float A[DSN], h[DSN], dtw[8];
  #pragma unroll
  for (int n = 0; n < DSN; ++n){ A[n] = -expf(A_log[d*DSN + n]); h[n] = 0.f; }
  #pragma unroll
  for (int r = 0; r < 8; ++r) dtw[r] = dt_w[r*DI + d];
  float dtb = dt_b[d], Dd = Dp[d];
  for (int l = 0; l < LL; ++l){
    int base = b*LL + l;
    float4 q[10];
    const float4* dr = (const float4*)(dbl + (size_t)base*40);
    #pragma unroll
    for (int i = 0; i < 10; ++i) q[i] = dr[i];
    const float* row = (const float*)q;
    float xi = xi2[(size_t)base*DI + d];
    float zs = zbuf[(size_t)base*DI + d];
    float dtp = dtb;
    #pragma unroll
    for (int r = 0; r < 8; ++r) dtp += row[r] * dtw[r];
    float dt = fmaxf(dtp, 0.f) + log1pf(expf(-fabsf(dtp)));  // stable softplus
    float dtxi = dt * xi;
    float y = 0.f;
    #pragma unroll
    for (int n = 0; n < DSN; ++n){
      float dA = expf(dt * A[n]);
      h[n] = dA * h[n] + dtxi * row[8 + n];
      y += h[n] * row[24 + n];
    }
    ybuf[(size_t)base*DI + d] = (y + Dd * xi) * zs;
  }
}

// ---------------- 8. out_layer dot + denorm + fc0 ----------------
__global__ void outlayer_kernel(const float* __restrict__ yout, const float* __restrict__ olw,
                                const float* __restrict__ stats, const float* __restrict__ fc0w,
                                const float* __restrict__ fc0b, float* __restrict__ h0){
  __shared__ float red[2];
  int row = blockIdx.x, t = threadIdx.x;   // 128 threads
  float v = yout[(size_t)row*DM + t] * olw[t];
  #pragma unroll
  for (int off = 32; off; off >>= 1) v += __shfl_down(v, off);
  if ((t & 63) == 0) red[t >> 6] = v;
  __syncthreads();
  if (t == 0){
    int b = row >> 9;
    float s = red[0] + red[1];
    float xo = s * stats[BB + b] + stats[b];
    float dec = fmaxf(xo, 0.f);
    h0[row] = fmaxf(dec * fc0w[0] + fc0b[0], 0.f);
  }
}

// ---------------- 9. final MLP per batch ----------------
__global__ __launch_bounds__(128) void mlp_kernel(const float* __restrict__ h0,
    const float* __restrict__ fc1w, const float* __restrict__ fc1b,
    const float* __restrict__ fc2w, const float* __restrict__ fc2b,
    const float* __restrict__ fc3w, const float* __restrict__ fc3b,
    float* __restrict__ out){
  __shared__ float h0s[LL];
  __shared__ float h1s[128];
  __shared__ float h2s[64];
  int b = blockIdx.x, t = threadIdx.x;
  #pragma unroll
  for (int i = 0; i < 4; ++i) h0s[t + i*128] = h0[b*LL + t + i*128];
  __syncthreads();
  float a = fc1b[t];
  for (int l = 0; l < LL; ++l) a += h0s[l] * fc1w[l*128 + t];
  h1s[t] = fmaxf(a, 0.f);
  __syncthreads();
  if (t < 64){
    float a2 = fc2b[t];
    #pragma unroll 4
    for (int k = 0; k < 128; ++k) a2 += h1s[k] * fc2w[k*64 + t];
    h2s[t] = fmaxf(a2, 0.f);
  }
  __syncthreads();
  if (t < 64){
    float p = h2s[t] * fc3w[t];
    #pragma unroll
    for (int off = 32; off; off >>= 1) p += __shfl_down(p, off);
    if (t == 0) out[b] = p + fc3b[0];
  }
}

extern "C" void kernel_launch(void* const* d_in, const int* in_sizes, int n_in,
                              void* d_out, int out_size, void* d_ws, size_t ws_size,
                              hipStream_t stream){
  const float* x_enc      = (const float*)d_in[0];
  const float* x_mark_enc = (const float*)d_in[1];
  const float* tok_w      = (const float*)d_in[4];
  const float* temp_w     = (const float*)d_in[5];
  const float* in_proj_w  = (const float*)d_in[6];
  const float* conv_w     = (const float*)d_in[7];
  const float* conv_b     = (const float*)d_in[8];
  const float* x_proj_w   = (const float*)d_in[9];
  const float* dt_w       = (const float*)d_in[10];
  const float* dt_b       = (const float*)d_in[11];
  const float* A_log      = (const float*)d_in[12];
  const float* Dp         = (const float*)d_in[13];
  const float* out_proj_w = (const float*)d_in[14];
  const float* out_lay_w  = (const float*)d_in[15];
  const float* fc0_w      = (const float*)d_in[16];
  const float* fc0_b      = (const float*)d_in[17];
  const float* fc1_w      = (const float*)d_in[18];
  const float* fc1_b      = (const float*)d_in[19];
  const float* fc2_w      = (const float*)d_in[20];
  const float* fc2_b      = (const float*)d_in[21];
  const float* fc3_w      = (const float*)d_in[22];
  const float* fc3_b      = (const float*)d_in[23];
  float* outp = (float*)d_out;

  float* ws = (float*)d_ws;
  float* xn     = ws;                                   // 16384
  float* stats  = xn + BB*LL;                           // 64
  float* xbuf   = stats + 64;                           // 16384*128
  float* xi_raw = xbuf + (size_t)BB*LL*DM;              // 16384*256
  float* zbuf   = xi_raw + (size_t)BB*LL*DI;            // 16384*256
  float* xi2    = zbuf + (size_t)BB*LL*DI;              // 16384*256
  float* dblb   = xi2 + (size_t)BB*LL*DI;               // 16384*40
  float* h0     = dblb + (size_t)BB*LL*40;              // 16384
  float* ybuf   = xi_raw;                               // reuse (dead after conv)
  float* yout   = xbuf;                                 // reuse (dead after in_proj gemm)

  const int M = BB*LL;

  norm_kernel<<<BB, 256, 0, stream>>>(x_enc, xn, stats);
  embed_kernel<<<M, DM, 0, stream>>>(xn, x_mark_enc, tok_w, temp_w, xbuf);
  gemm64_kernel<1><<<dim3(M/64, 8), 256, 0, stream>>>(xbuf, in_proj_w, xi_raw, zbuf, M, 512, DM);
  conv_kernel<<<M, DI, 0, stream>>>(xi_raw, conv_w, conv_b, xi2);
  dbl_kernel<<<M/64, 256, 0, stream>>>(xi2, x_proj_w, dblb);
  scan_kernel<<<BB, DI, 0, stream>>>(xi2, zbuf, dblb, A_log, dt_w, dt_b, Dp, ybuf);
  gemm64_kernel<0><<<dim3(M/64, 2), 256, 0, stream>>>(ybuf, out_proj_w, yout, nullptr, M, DM, DI);
  outlayer_kernel<<<M, DM, 0, stream>>>(yout, out_lay_w, stats, fc0_w, fc0_b, h0);
  mlp_kernel<<<BB, 128, 0, stream>>>(h0, fc1_w, fc1_b, fc2_w, fc2_b, fc3_w, fc3_b, outp);
}

// Round 2
// 537.882 us; speedup vs baseline: 1.5423x; 1.5423x over previous
//
#include <hip/hip_runtime.h>
#include <math.h>

#define BB 32
#define LL 512
#define DM 128
#define DI 256
#define DSN 16
#define NMK 4

__device__ __forceinline__ float silu_f(float x){ return x / (1.f + expf(-x)); }

// ---------------- 1. per-batch normalization ----------------
__global__ void norm_kernel(const float* __restrict__ x_enc,
                            float* __restrict__ xn, float* __restrict__ stats){
  __shared__ float xs[LL];
  __shared__ float red[256];
  int b = blockIdx.x, t = threadIdx.x;
  xs[t]       = x_enc[b*LL + t];
  xs[t + 256] = x_enc[b*LL + t + 256];
  __syncthreads();
  red[t] = xs[t] + xs[t + 256];
  __syncthreads();
  for (int s = 128; s; s >>= 1){ if (t < s) red[t] += red[t + s]; __syncthreads(); }
  float mean = red[0] / (float)LL;
  __syncthreads();
  float xc0 = xs[t] - mean, xc1 = xs[t + 256] - mean;
  red[t] = xc0*xc0 + xc1*xc1;
  __syncthreads();
  for (int s = 128; s; s >>= 1){ if (t < s) red[t] += red[t + s]; __syncthreads(); }
  float var = red[0] / (float)LL;
  float sd = sqrtf(var + 1e-5f);
  xn[b*LL + t]       = xc0 / sd;
  xn[b*LL + t + 256] = xc1 / sd;
  if (t == 0){ stats[b] = mean; stats[BB + b] = sd; }
}

// ---------------- 2. token conv + temporal + positional embedding ----------------
__global__ void embed_kernel(const float* __restrict__ xn, const float* __restrict__ xmark,
                             const float* __restrict__ tok_w, const float* __restrict__ temp_w,
                             float* __restrict__ xbuf){
  int row = blockIdx.x;          // b*LL + l
  int o = threadIdx.x;           // 0..127
  int b = row >> 9, l = row & 511;
  float xm1 = xn[b*LL + ((l == 0) ? (LL - 1) : (l - 1))];
  float x0  = xn[row];
  float xp1 = xn[b*LL + ((l == LL - 1) ? 0 : (l + 1))];
  float v = xm1 * tok_w[o*3 + 0] + x0 * tok_w[o*3 + 1] + xp1 * tok_w[o*3 + 2];
  #pragma unroll
  for (int m = 0; m < NMK; ++m) v += xmark[row*NMK + m] * temp_w[m*DM + o];
  int i = o >> 1;
  float ang = (float)l * expf((float)(2*i) * -0.07195578415606394f); // -ln(10000)/128
  v += (o & 1) ? cosf(ang) : sinf(ang);
  xbuf[row*DM + o] = v;
}

// ---------------- 3/7. tiled f32 GEMM, 64x64 tile, 256 thr ----------------
template<int MODE>
__global__ __launch_bounds__(256) void gemm64_kernel(const float* __restrict__ A,
    const float* __restrict__ W, float* __restrict__ out0, float* __restrict__ out1,
    int M, int N, int K){
  __shared__ float AsT[32][68];
  __shared__ float Bs[32][64];
  int tid = threadIdx.x;
  int tx = tid & 15, ty = tid >> 4;
  int rowBase = blockIdx.x * 64, colBase = blockIdx.y * 64;
  float acc[4][4] = {};
  for (int kc = 0; kc < K; kc += 32){
    #pragma unroll
    for (int i = 0; i < 8; ++i){
      int idx = tid + i*256;
      int r = idx >> 5, k = idx & 31;
      AsT[k][r] = A[(size_t)(rowBase + r)*K + kc + k];
    }
    #pragma unroll
    for (int i = 0; i < 8; ++i){
      int idx = tid + i*256;
      int k = idx >> 6, c = idx & 63;
      Bs[k][c] = W[(size_t)(kc + k)*N + colBase + c];
    }
    __syncthreads();
    #pragma unroll
    for (int k = 0; k < 32; ++k){
      float4 a  = *(const float4*)&AsT[k][ty*4];
      float4 bv = *(const float4*)&Bs[k][tx*4];
      float av[4] = {a.x, a.y, a.z, a.w};
      float bb[4] = {bv.x, bv.y, bv.z, bv.w};
      #pragma unroll
      for (int ii = 0; ii < 4; ++ii)
        #pragma unroll
        for (int jj = 0; jj < 4; ++jj) acc[ii][jj] += av[ii]*bb[jj];
    }
    __syncthreads();
  }
  #pragma unroll
  for (int ii = 0; ii < 4; ++ii){
    int row = rowBase + ty*4 + ii;
    #pragma unroll
    for (int jj = 0; jj < 4; ++jj){
      int col = colBase + tx*4 + jj;
      float v = acc[ii][jj];
      if (MODE == 0){
        out0[(size_t)row*N + col] = v;
      } else {
        if (col < DI) out0[(size_t)row*DI + col] = v;
        else          out1[(size_t)row*DI + col - DI] = silu_f(v);
      }
    }
  }
}

// ---------------- 4. depthwise causal conv + silu ----------------
__global__ void conv_kernel(const float* __restrict__ xi_raw, const float* __restrict__ conv_w,
                            const float* __restrict__ conv_b, float* __restrict__ xi2){
  int row = blockIdx.x, d = threadIdx.x;
  int l = row & 511;
  float acc = conv_b[d];
  #pragma unroll
  for (int k = 0; k < 4; ++k){
    int t = l + k - 3;
    if (t >= 0) acc += xi_raw[(size_t)(row + k - 3)*DI + d] * conv_w[d*4 + k];
  }
  xi2[(size_t)row*DI + d] = silu_f(acc);
}

// ---------------- 5. dbl = xi2 @ x_proj_w  (M=16384, N=40, K=256) ----------------
__global__ __launch_bounds__(256) void dbl_kernel(const float* __restrict__ xi2,
    const float* __restrict__ xpw, float* __restrict__ dbl){
  __shared__ float Xs[64][65];
  __shared__ float Ws[64][48];
  int t = threadIdx.x;
  int r = t >> 2, g = t & 3;
  int rowBase = blockIdx.x * 64;
  float acc[12] = {};
  for (int kc = 0; kc < DI; kc += 64){
    #pragma unroll
    for (int i = 0; i < 16; ++i){
      int idx = t + i*256;
      int rr = idx >> 6, k = idx & 63;
      Xs[k][rr] = xi2[(size_t)(rowBase + rr)*DI + kc + k];
    }
    #pragma unroll
    for (int i = 0; i < 12; ++i){
      int idx = t + i*256;
      int k = idx / 48, j = idx % 48;
      Ws[k][j] = (j < 40) ? xpw[(kc + k)*40 + j] : 0.f;
    }
    __syncthreads();
    for (int k = 0; k < 64; ++k){
      float a = Xs[k][r];
      const float4* wr = (const float4*)&Ws[k][g*12];
      float4 w0 = wr[0], w1 = wr[1], w2 = wr[2];
      acc[0]  += a*w0.x; acc[1]  += a*w0.y; acc[2]  += a*w0.z; acc[3]  += a*w0.w;
      acc[4]  += a*w1.x; acc[5]  += a*w1.y; acc[6]  += a*w1.z; acc[7]  += a*w1.w;
      acc[8]  += a*w2.x; acc[9]  += a*w2.y; acc[10] += a*w2.z; acc[11] += a*w2.w;
    }
    __syncthreads();
  }
  int row = rowBase + r;
  #pragma unroll
  for (int jj = 0; jj < 12; ++jj){
    int j = g*12 + jj;
    if (j < 40) dbl[(size_t)row*40 + j] = acc[jj];
  }
}

// ---------------- 5b. dt precompute: dt = softplus(dbl[:, :8] @ dt_w + dt_b) ----------------
__global__ __launch_bounds__(256) void dt_kernel(const float* __restrict__ dbl,
    const float* __restrict__ dt_w, const float* __restrict__ dt_b,
    float* __restrict__ dtpre){
  __shared__ float rowp[8];
  int row = blockIdx.x, t = threadIdx.x;
  if (t < 8) rowp[t] = dbl[(size_t)row*40 + t];
  __syncthreads();
  float dtp = dt_b[t];
  #pragma unroll
  for (int r = 0; r < 8; ++r) dtp += rowp[r] * dt_w[r*DI + t];
  // stable softplus
  float dt = fmaxf(dtp, 0.f) + log1pf(expf(-fabsf(dtp)));
  dtpre[(size_t)row*DI + t] = dt;
}

// ---------------- 6. state-parallel selective scan ----------------
// thread = (b, d, n): lane group of 16 = the 16 states of one (b,d) channel.
// block 256 = 16 d-channels x 16 states; grid (BB, DI/16).
__global__ __launch_bounds__(256) void scan_n_kernel(const float* __restrict__ dtpre,
    const float* __restrict__ xi2, const float* __restrict__ zbuf,
    const float* __restrict__ dbl, const float* __restrict__ A_log,
    const float* __restrict__ Dp, float* __restrict__ ybuf){
  int t = threadIdx.x;
  int n = t & 15, dl = t >> 4;
  int d = blockIdx.y * 16 + dl;
  int b = blockIdx.x;
  float A = -expf(A_log[d*DSN + n]);
  float Dd = Dp[d];
  float h = 0.f;
  const size_t rb = (size_t)b * LL;
  #pragma unroll 4
  for (int l = 0; l < LL; ++l){
    size_t base = rb + l;
    float dtv = dtpre[base*DI + d];           // broadcast within 16 lanes
    float Bv  = dbl[base*40 + 8 + n];
    float Cv  = dbl[base*40 + 24 + n];
    float xiv = xi2[base*DI + d];             // broadcast
    float dA  = expf(dtv * A);
    h = dA * h + (dtv * xiv) * Bv;
    float p = h * Cv;
    p += __shfl_xor(p, 8, 16);
    p += __shfl_xor(p, 4, 16);
    p += __shfl_xor(p, 2, 16);
    p += __shfl_xor(p, 1, 16);
    if (n == 0){
      float zs = zbuf[base*DI + d];
      ybuf[base*DI + d] = (p + Dd * xiv) * zs;
    }
  }
}

// ---------------- 8. out_layer dot + denorm + fc0 ----------------
__global__ void outlayer_kernel(const float* __restrict__ yout, const float* __restrict__ olw,
                                const float* __restrict__ stats, const float* __restrict__ fc0w,
                                const float* __restrict__ fc0b, float* __restrict__ h0){
  __shared__ float red[2];
  int row = blockIdx.x, t = threadIdx.x;   // 128 threads
  float v = yout[(size_t)row*DM + t] * olw[t];
  #pragma unroll
  for (int off = 32; off; off >>= 1) v += __shfl_down(v, off);
  if ((t & 63) == 0) red[t >> 6] = v;
  __syncthreads();
  if (t == 0){
    int b = row >> 9;
    float s = red[0] + red[1];
    float xo = s * stats[BB + b] + stats[b];
    float dec = fmaxf(xo, 0.f);
    h0[row] = fmaxf(dec * fc0w[0] + fc0b[0], 0.f);
  }
}

// ---------------- 9. final MLP per batch ----------------
__global__ __launch_bounds__(128) void mlp_kernel(const float* __restrict__ h0,
    const float* __restrict__ fc1w, const float* __restrict__ fc1b,
    const float* __restrict__ fc2w, const float* __restrict__ fc2b,
    const float* __restrict__ fc3w, const float* __restrict__ fc3b,
    float* __restrict__ out){
  __shared__ float h0s[LL];
  __shared__ float h1s[128];
  __shared__ float h2s[64];
  int b = blockIdx.x, t = threadIdx.x;
  #pragma unroll
  for (int i = 0; i < 4; ++i) h0s[t + i*128] = h0[b*LL + t + i*128];
  __syncthreads();
  float a = fc1b[t];
  for (int l = 0; l < LL; ++l) a += h0s[l] * fc1w[l*128 + t];
  h1s[t] = fmaxf(a, 0.f);
  __syncthreads();
  if (t < 64){
    float a2 = fc2b[t];
    #pragma unroll 4
    for (int k = 0; k < 128; ++k) a2 += h1s[k] * fc2w[k*64 + t];
    h2s[t] = fmaxf(a2, 0.f);
  }
  __syncthreads();
  if (t < 64){
    float p = h2s[t] * fc3w[t];
    #pragma unroll
    for (int off = 32; off; off >>= 1) p += __shfl_down(p, off);
    if (t == 0) out[b] = p + fc3b[0];
  }
}

extern "C" void kernel_launch(void* const* d_in, const int* in_sizes, int n_in,
                              void* d_out, int out_size, void* d_ws, size_t ws_size,
                              hipStream_t stream){
  const float* x_enc      = (const float*)d_in[0];
  const float* x_mark_enc = (const float*)d_in[1];
  const float* tok_w      = (const float*)d_in[4];
  const float* temp_w     = (const float*)d_in[5];
  const float* in_proj_w  = (const float*)d_in[6];
  const float* conv_w     = (const float*)d_in[7];
  const float* conv_b     = (const float*)d_in[8];
  const float* x_proj_w   = (const float*)d_in[9];
  const float* dt_w       = (const float*)d_in[10];
  const float* dt_b       = (const float*)d_in[11];
  const float* A_log      = (const float*)d_in[12];
  const float* Dp         = (const float*)d_in[13];
  const float* out_proj_w = (const float*)d_in[14];
  const float* out_lay_w  = (const float*)d_in[15];
  const float* fc0_w      = (const float*)d_in[16];
  const float* fc0_b      = (const float*)d_in[17];
  const float* fc1_w      = (const float*)d_in[18];
  const float* fc1_b      = (const float*)d_in[19];
  const float* fc2_w      = (const float*)d_in[20];
  const float* fc2_b      = (const float*)d_in[21];
  const float* fc3_w      = (const float*)d_in[22];
  const float* fc3_b      = (const float*)d_in[23];
  float* outp = (float*)d_out;

  float* ws = (float*)d_ws;
  const int M = BB*LL;
  float* xn     = ws;                                   // M
  float* stats  = xn + M;                               // 64
  float* xbuf   = stats + 64;                           // M*128
  float* xi_raw = xbuf + (size_t)M*DM;                  // M*256
  float* zbuf   = xi_raw + (size_t)M*DI;                // M*256
  float* xi2    = zbuf + (size_t)M*DI;                  // M*256
  float* dblb   = xi2 + (size_t)M*DI;                   // M*40
  float* dtpre  = dblb + (size_t)M*40;                  // M*256
  float* h0     = dtpre + (size_t)M*DI;                 // M
  float* ybuf   = xi_raw;                               // reuse (dead after conv)
  float* yout   = xbuf;                                 // reuse (dead after in_proj)

  norm_kernel<<<BB, 256, 0, stream>>>(x_enc, xn, stats);
  embed_kernel<<<M, DM, 0, stream>>>(xn, x_mark_enc, tok_w, temp_w, xbuf);
  gemm64_kernel<1><<<dim3(M/64, 8), 256, 0, stream>>>(xbuf, in_proj_w, xi_raw, zbuf, M, 512, DM);
  conv_kernel<<<M, DI, 0, stream>>>(xi_raw, conv_w, conv_b, xi2);
  dbl_kernel<<<M/64, 256, 0, stream>>>(xi2, x_proj_w, dblb);
  dt_kernel<<<M, DI, 0, stream>>>(dblb, dt_w, dt_b, dtpre);
  scan_n_kernel<<<dim3(BB, DI/16), 256, 0, stream>>>(dtpre, xi2, zbuf, dblb, A_log, Dp, ybuf);
  gemm64_kernel<0><<<dim3(M/64, 2), 256, 0, stream>>>(ybuf, out_proj_w, yout, nullptr, M, DM, DI);
  outlayer_kernel<<<M, DM, 0, stream>>>(yout, out_lay_w, stats, fc0_w, fc0_b, h0);
  mlp_kernel<<<BB, 128, 0, stream>>>(h0, fc1_w, fc1_b, fc2_w, fc2_b, fc3_w, fc3_b, outp);
}

// Round 3
// 323.244 us; speedup vs baseline: 2.5665x; 1.6640x over previous
//
#include <hip/hip_runtime.h>
#include <math.h>

#define BB 32
#define LL 512
#define DM 128
#define DI 256
#define DSN 16
#define NMK 4
#define NC 8
#define CL 64   // LL/NC

__device__ __forceinline__ float silu_f(float x){ return x / (1.f + expf(-x)); }

// ---------------- 1. per-batch normalization ----------------
__global__ void norm_kernel(const float* __restrict__ x_enc,
                            float* __restrict__ xn, float* __restrict__ stats){
  __shared__ float xs[LL];
  __shared__ float red[256];
  int b = blockIdx.x, t = threadIdx.x;
  xs[t]       = x_enc[b*LL + t];
  xs[t + 256] = x_enc[b*LL + t + 256];
  __syncthreads();
  red[t] = xs[t] + xs[t + 256];
  __syncthreads();
  for (int s = 128; s; s >>= 1){ if (t < s) red[t] += red[t + s]; __syncthreads(); }
  float mean = red[0] / (float)LL;
  __syncthreads();
  float xc0 = xs[t] - mean, xc1 = xs[t + 256] - mean;
  red[t] = xc0*xc0 + xc1*xc1;
  __syncthreads();
  for (int s = 128; s; s >>= 1){ if (t < s) red[t] += red[t + s]; __syncthreads(); }
  float var = red[0] / (float)LL;
  float sd = sqrtf(var + 1e-5f);
  xn[b*LL + t]       = xc0 / sd;
  xn[b*LL + t + 256] = xc1 / sd;
  if (t == 0){ stats[b] = mean; stats[BB + b] = sd; }
}

// ---------------- 2. token conv + temporal + positional embedding ----------------
__global__ void embed_kernel(const float* __restrict__ xn, const float* __restrict__ xmark,
                             const float* __restrict__ tok_w, const float* __restrict__ temp_w,
                             float* __restrict__ xbuf){
  int row = blockIdx.x;          // b*LL + l
  int o = threadIdx.x;           // 0..127
  int b = row >> 9, l = row & 511;
  float xm1 = xn[b*LL + ((l == 0) ? (LL - 1) : (l - 1))];
  float x0  = xn[row];
  float xp1 = xn[b*LL + ((l == LL - 1) ? 0 : (l + 1))];
  float v = xm1 * tok_w[o*3 + 0] + x0 * tok_w[o*3 + 1] + xp1 * tok_w[o*3 + 2];
  #pragma unroll
  for (int m = 0; m < NMK; ++m) v += xmark[row*NMK + m] * temp_w[m*DM + o];
  int i = o >> 1;
  float ang = (float)l * expf((float)(2*i) * -0.07195578415606394f); // -ln(10000)/128
  v += (o & 1) ? cosf(ang) : sinf(ang);
  xbuf[row*DM + o] = v;
}

// ---------------- 3/7. tiled f32 GEMM, 64x64 tile, 256 thr ----------------
template<int MODE>
__global__ __launch_bounds__(256) void gemm64_kernel(const float* __restrict__ A,
    const float* __restrict__ W, float* __restrict__ out0, float* __restrict__ out1,
    int M, int N, int K){
  __shared__ float AsT[32][68];
  __shared__ float Bs[32][64];
  int tid = threadIdx.x;
  int tx = tid & 15, ty = tid >> 4;
  int rowBase = blockIdx.x * 64, colBase = blockIdx.y * 64;
  float acc[4][4] = {};
  for (int kc = 0; kc < K; kc += 32){
    #pragma unroll
    for (int i = 0; i < 8; ++i){
      int idx = tid + i*256;
      int r = idx >> 5, k = idx & 31;
      AsT[k][r] = A[(size_t)(rowBase + r)*K + kc + k];
    }
    #pragma unroll
    for (int i = 0; i < 8; ++i){
      int idx = tid + i*256;
      int k = idx >> 6, c = idx & 63;
      Bs[k][c] = W[(size_t)(kc + k)*N + colBase + c];
    }
    __syncthreads();
    #pragma unroll
    for (int k = 0; k < 32; ++k){
      float4 a  = *(const float4*)&AsT[k][ty*4];
      float4 bv = *(const float4*)&Bs[k][tx*4];
      float av[4] = {a.x, a.y, a.z, a.w};
      float bb[4] = {bv.x, bv.y, bv.z, bv.w};
      #pragma unroll
      for (int ii = 0; ii < 4; ++ii)
        #pragma unroll
        for (int jj = 0; jj < 4; ++jj) acc[ii][jj] += av[ii]*bb[jj];
    }
    __syncthreads();
  }
  #pragma unroll
  for (int ii = 0; ii < 4; ++ii){
    int row = rowBase + ty*4 + ii;
    #pragma unroll
    for (int jj = 0; jj < 4; ++jj){
      int col = colBase + tx*4 + jj;
      float v = acc[ii][jj];
      if (MODE == 0){
        out0[(size_t)row*N + col] = v;
      } else {
        if (col < DI) out0[(size_t)row*DI + col] = v;
        else          out1[(size_t)row*DI + col - DI] = silu_f(v);
      }
    }
  }
}

// ---------------- 4. depthwise causal conv + silu ----------------
__global__ void conv_kernel(const float* __restrict__ xi_raw, const float* __restrict__ conv_w,
                            const float* __restrict__ conv_b, float* __restrict__ xi2){
  int row = blockIdx.x, d = threadIdx.x;
  int l = row & 511;
  float acc = conv_b[d];
  #pragma unroll
  for (int k = 0; k < 4; ++k){
    int t = l + k - 3;
    if (t >= 0) acc += xi_raw[(size_t)(row + k - 3)*DI + d] * conv_w[d*4 + k];
  }
  xi2[(size_t)row*DI + d] = silu_f(acc);
}

// ---------------- 5. dbl = xi2 @ x_proj_w  (M=16384, N=40, K=256) ----------------
__global__ __launch_bounds__(256) void dbl_kernel(const float* __restrict__ xi2,
    const float* __restrict__ xpw, float* __restrict__ dbl){
  __shared__ float Xs[64][65];
  __shared__ float Ws[64][48];
  int t = threadIdx.x;
  int r = t >> 2, g = t & 3;
  int rowBase = blockIdx.x * 64;
  float acc[12] = {};
  for (int kc = 0; kc < DI; kc += 64){
    #pragma unroll
    for (int i = 0; i < 16; ++i){
      int idx = t + i*256;
      int rr = idx >> 6, k = idx & 63;
      Xs[k][rr] = xi2[(size_t)(rowBase + rr)*DI + kc + k];
    }
    #pragma unroll
    for (int i = 0; i < 12; ++i){
      int idx = t + i*256;
      int k = idx / 48, j = idx % 48;
      Ws[k][j] = (j < 40) ? xpw[(kc + k)*40 + j] : 0.f;
    }
    __syncthreads();
    for (int k = 0; k < 64; ++k){
      float a = Xs[k][r];
      const float4* wr = (const float4*)&Ws[k][g*12];
      float4 w0 = wr[0], w1 = wr[1], w2 = wr[2];
      acc[0]  += a*w0.x; acc[1]  += a*w0.y; acc[2]  += a*w0.z; acc[3]  += a*w0.w;
      acc[4]  += a*w1.x; acc[5]  += a*w1.y; acc[6]  += a*w1.z; acc[7]  += a*w1.w;
      acc[8]  += a*w2.x; acc[9]  += a*w2.y; acc[10] += a*w2.z; acc[11] += a*w2.w;
    }
    __syncthreads();
  }
  int row = rowBase + r;
  #pragma unroll
  for (int jj = 0; jj < 12; ++jj){
    int j = g*12 + jj;
    if (j < 40) dbl[(size_t)row*40 + j] = acc[jj];
  }
}

// ---------------- 5b. dt precompute ----------------
__global__ __launch_bounds__(256) void dt_kernel(const float* __restrict__ dbl,
    const float* __restrict__ dt_w, const float* __restrict__ dt_b,
    float* __restrict__ dtpre){
  __shared__ float rowp[8];
  int row = blockIdx.x, t = threadIdx.x;
  if (t < 8) rowp[t] = dbl[(size_t)row*40 + t];
  __syncthreads();
  float dtp = dt_b[t];
  #pragma unroll
  for (int r = 0; r < 8; ++r) dtp += rowp[r] * dt_w[r*DI + t];
  float dt = fmaxf(dtp, 0.f) + log1pf(expf(-fabsf(dtp)));
  dtpre[(size_t)row*DI + t] = dt;
}

// ---------------- 6a. chunk-local scan: hend + decay product ----------------
// grid (BB, DI/16, NC), block 256 = 16 d x 16 n
__global__ __launch_bounds__(256) void scan_part1_kernel(const float* __restrict__ dtpre,
    const float* __restrict__ xi2, const float* __restrict__ dbl,
    const float* __restrict__ A_log, float* __restrict__ hend, float* __restrict__ Pprod){
  int t = threadIdx.x;
  int n = t & 15, dl = t >> 4;
  int d = blockIdx.y * 16 + dl;
  int b = blockIdx.x, j = blockIdx.z;
  float A = -expf(A_log[d*DSN + n]);
  float h = 0.f, dtsum = 0.f;
  const size_t rb = (size_t)b * LL + (size_t)j * CL;
  #pragma unroll 4
  for (int l = 0; l < CL; ++l){
    size_t base = rb + l;
    float dtv = dtpre[base*DI + d];
    float Bv  = dbl[base*40 + 8 + n];
    float xiv = xi2[base*DI + d];
    float dA  = expf(dtv * A);
    h = dA * h + (dtv * xiv) * Bv;
    dtsum += dtv;
  }
  size_t idx = (((size_t)b*DI + d)*DSN + n)*NC + j;
  hend[idx]  = h;
  Pprod[idx] = expf(A * dtsum);
}

// ---------------- 6b. carry scan across chunks (in-place: hend <- carry-in) ----------------
__global__ void carry_kernel(float* __restrict__ hend, const float* __restrict__ Pprod){
  int idx = blockIdx.x*256 + threadIdx.x;   // (b*DI+d)*DSN+n
  size_t base = (size_t)idx * NC;
  float c = 0.f;
  #pragma unroll
  for (int j = 0; j < NC; ++j){
    float he = hend[base + j];
    float P  = Pprod[base + j];
    hend[base + j] = c;       // carry-in for chunk j
    c = P * c + he;
  }
}

// ---------------- 6c. final scan per chunk from carry-in ----------------
__global__ __launch_bounds__(256) void scan_part2_kernel(const float* __restrict__ dtpre,
    const float* __restrict__ xi2, const float* __restrict__ zbuf,
    const float* __restrict__ dbl, const float* __restrict__ A_log,
    const float* __restrict__ Dp, const float* __restrict__ cin,
    float* __restrict__ ybuf){
  int t = threadIdx.x;
  int n = t & 15, dl = t >> 4;
  int d = blockIdx.y * 16 + dl;
  int b = blockIdx.x, j = blockIdx.z;
  float A = -expf(A_log[d*DSN + n]);
  float Dd = Dp[d];
  float h = cin[(((size_t)b*DI + d)*DSN + n)*NC + j];
  const size_t rb = (size_t)b * LL + (size_t)j * CL;
  #pragma unroll 4
  for (int l = 0; l < CL; ++l){
    size_t base = rb + l;
    float dtv = dtpre[base*DI + d];
    float Bv  = dbl[base*40 + 8 + n];
    float Cv  = dbl[base*40 + 24 + n];
    float xiv = xi2[base*DI + d];
    float dA  = expf(dtv * A);
    h = dA * h + (dtv * xiv) * Bv;
    float p = h * Cv;
    p += __shfl_xor(p, 8, 16);
    p += __shfl_xor(p, 4, 16);
    p += __shfl_xor(p, 2, 16);
    p += __shfl_xor(p, 1, 16);
    if (n == 0){
      float zs = zbuf[base*DI + d];
      ybuf[base*DI + d] = (p + Dd * xiv) * zs;
    }
  }
}

// ---------------- 8. out_layer dot + denorm + fc0 ----------------
__global__ void outlayer_kernel(const float* __restrict__ yout, const float* __restrict__ olw,
                                const float* __restrict__ stats, const float* __restrict__ fc0w,
                                const float* __restrict__ fc0b, float* __restrict__ h0){
  __shared__ float red[2];
  int row = blockIdx.x, t = threadIdx.x;   // 128 threads
  float v = yout[(size_t)row*DM + t] * olw[t];
  #pragma unroll
  for (int off = 32; off; off >>= 1) v += __shfl_down(v, off);
  if ((t & 63) == 0) red[t >> 6] = v;
  __syncthreads();
  if (t == 0){
    int b = row >> 9;
    float s = red[0] + red[1];
    float xo = s * stats[BB + b] + stats[b];
    float dec = fmaxf(xo, 0.f);
    h0[row] = fmaxf(dec * fc0w[0] + fc0b[0], 0.f);
  }
}

// ---------------- 9. final MLP per batch ----------------
__global__ __launch_bounds__(128) void mlp_kernel(const float* __restrict__ h0,
    const float* __restrict__ fc1w, const float* __restrict__ fc1b,
    const float* __restrict__ fc2w, const float* __restrict__ fc2b,
    const float* __restrict__ fc3w, const float* __restrict__ fc3b,
    float* __restrict__ out){
  __shared__ float h0s[LL];
  __shared__ float h1s[128];
  __shared__ float h2s[64];
  int b = blockIdx.x, t = threadIdx.x;
  #pragma unroll
  for (int i = 0; i < 4; ++i) h0s[t + i*128] = h0[b*LL + t + i*128];
  __syncthreads();
  float a = fc1b[t];
  for (int l = 0; l < LL; ++l) a += h0s[l] * fc1w[l*128 + t];
  h1s[t] = fmaxf(a, 0.f);
  __syncthreads();
  if (t < 64){
    float a2 = fc2b[t];
    #pragma unroll 4
    for (int k = 0; k < 128; ++k) a2 += h1s[k] * fc2w[k*64 + t];
    h2s[t] = fmaxf(a2, 0.f);
  }
  __syncthreads();
  if (t < 64){
    float p = h2s[t] * fc3w[t];
    #pragma unroll
    for (int off = 32; off; off >>= 1) p += __shfl_down(p, off);
    if (t == 0) out[b] = p + fc3b[0];
  }
}

extern "C" void kernel_launch(void* const* d_in, const int* in_sizes, int n_in,
                              void* d_out, int out_size, void* d_ws, size_t ws_size,
                              hipStream_t stream){
  const float* x_enc      = (const float*)d_in[0];
  const float* x_mark_enc = (const float*)d_in[1];
  const float* tok_w      = (const float*)d_in[4];
  const float* temp_w     = (const float*)d_in[5];
  const float* in_proj_w  = (const float*)d_in[6];
  const float* conv_w     = (const float*)d_in[7];
  const float* conv_b     = (const float*)d_in[8];
  const float* x_proj_w   = (const float*)d_in[9];
  const float* dt_w       = (const float*)d_in[10];
  const float* dt_b       = (const float*)d_in[11];
  const float* A_log      = (const float*)d_in[12];
  const float* Dp         = (const float*)d_in[13];
  const float* out_proj_w = (const float*)d_in[14];
  const float* out_lay_w  = (const float*)d_in[15];
  const float* fc0_w      = (const float*)d_in[16];
  const float* fc0_b      = (const float*)d_in[17];
  const float* fc1_w      = (const float*)d_in[18];
  const float* fc1_b      = (const float*)d_in[19];
  const float* fc2_w      = (const float*)d_in[20];
  const float* fc2_b      = (const float*)d_in[21];
  const float* fc3_w      = (const float*)d_in[22];
  const float* fc3_b      = (const float*)d_in[23];
  float* outp = (float*)d_out;

  float* ws = (float*)d_ws;
  const int M = BB*LL;
  float* xn     = ws;                                   // M
  float* stats  = xn + M;                               // 64
  float* xbuf   = stats + 64;                           // M*128 (8MB)
  float* xi_raw = xbuf + (size_t)M*DM;                  // M*256
  float* zbuf   = xi_raw + (size_t)M*DI;                // M*256
  float* xi2    = zbuf + (size_t)M*DI;                  // M*256
  float* dblb   = xi2 + (size_t)M*DI;                   // M*40
  float* dtpre  = dblb + (size_t)M*40;                  // M*256
  float* h0     = dtpre + (size_t)M*DI;                 // M
  float* ybuf   = xi_raw;                               // reuse (dead after conv)
  float* yout   = xbuf;                                 // reuse (dead after scan)
  // hend/Pprod live in xbuf (dead between in_proj gemm and out_proj gemm):
  // BB*DI*DSN*NC = 32*256*16*8 = 1M floats each, 8MB total = exactly xbuf
  float* hend   = xbuf;
  float* Pprod  = xbuf + (size_t)BB*DI*DSN*NC;

  norm_kernel<<<BB, 256, 0, stream>>>(x_enc, xn, stats);
  embed_kernel<<<M, DM, 0, stream>>>(xn, x_mark_enc, tok_w, temp_w, xbuf);
  gemm64_kernel<1><<<dim3(M/64, 8), 256, 0, stream>>>(xbuf, in_proj_w, xi_raw, zbuf, M, 512, DM);
  conv_kernel<<<M, DI, 0, stream>>>(xi_raw, conv_w, conv_b, xi2);
  dbl_kernel<<<M/64, 256, 0, stream>>>(xi2, x_proj_w, dblb);
  dt_kernel<<<M, DI, 0, stream>>>(dblb, dt_w, dt_b, dtpre);
  scan_part1_kernel<<<dim3(BB, DI/16, NC), 256, 0, stream>>>(dtpre, xi2, dblb, A_log, hend, Pprod);
  carry_kernel<<<BB*DI*DSN/256, 256, 0, stream>>>(hend, Pprod);
  scan_part2_kernel<<<dim3(BB, DI/16, NC), 256, 0, stream>>>(dtpre, xi2, zbuf, dblb, A_log, Dp, hend, ybuf);
  gemm64_kernel<0><<<dim3(M/64, 2), 256, 0, stream>>>(ybuf, out_proj_w, yout, nullptr, M, DM, DI);
  outlayer_kernel<<<M, DM, 0, stream>>>(yout, out_lay_w, stats, fc0_w, fc0_b, h0);
  mlp_kernel<<<BB, 128, 0, stream>>>(h0, fc1_w, fc1_b, fc2_w, fc2_b, fc3_w, fc3_b, outp);
}

// Round 4
// 285.237 us; speedup vs baseline: 2.9084x; 1.1332x over previous
//
#include <hip/hip_runtime.h>
#include <math.h>

#define BB 32
#define LL 512
#define DM 128
#define DI 256
#define DSN 16
#define NMK 4
#define NC 8
#define CL 64   // LL/NC

__device__ __forceinline__ float silu_f(float x){ return x / (1.f + expf(-x)); }

// ---------------- 1. per-batch normalization ----------------
__global__ void norm_kernel(const float* __restrict__ x_enc,
                            float* __restrict__ xn, float* __restrict__ stats){
  __shared__ float xs[LL];
  __shared__ float red[256];
  int b = blockIdx.x, t = threadIdx.x;
  xs[t]       = x_enc[b*LL + t];
  xs[t + 256] = x_enc[b*LL + t + 256];
  __syncthreads();
  red[t] = xs[t] + xs[t + 256];
  __syncthreads();
  for (int s = 128; s; s >>= 1){ if (t < s) red[t] += red[t + s]; __syncthreads(); }
  float mean = red[0] / (float)LL;
  __syncthreads();
  float xc0 = xs[t] - mean, xc1 = xs[t + 256] - mean;
  red[t] = xc0*xc0 + xc1*xc1;
  __syncthreads();
  for (int s = 128; s; s >>= 1){ if (t < s) red[t] += red[t + s]; __syncthreads(); }
  float var = red[0] / (float)LL;
  float sd = sqrtf(var + 1e-5f);
  xn[b*LL + t]       = xc0 / sd;
  xn[b*LL + t + 256] = xc1 / sd;
  if (t == 0){ stats[b] = mean; stats[BB + b] = sd; }
}

// ---------------- 2. token conv + temporal + positional embedding ----------------
__global__ void embed_kernel(const float* __restrict__ xn, const float* __restrict__ xmark,
                             const float* __restrict__ tok_w, const float* __restrict__ temp_w,
                             float* __restrict__ xbuf){
  int row = blockIdx.x;          // b*LL + l
  int o = threadIdx.x;           // 0..127
  int b = row >> 9, l = row & 511;
  float xm1 = xn[b*LL + ((l == 0) ? (LL - 1) : (l - 1))];
  float x0  = xn[row];
  float xp1 = xn[b*LL + ((l == LL - 1) ? 0 : (l + 1))];
  float v = xm1 * tok_w[o*3 + 0] + x0 * tok_w[o*3 + 1] + xp1 * tok_w[o*3 + 2];
  #pragma unroll
  for (int m = 0; m < NMK; ++m) v += xmark[row*NMK + m] * temp_w[m*DM + o];
  int i = o >> 1;
  float ang = (float)l * expf((float)(2*i) * -0.07195578415606394f); // -ln(10000)/128
  v += (o & 1) ? cosf(ang) : sinf(ang);
  xbuf[row*DM + o] = v;
}

// ---------------- 3/7. tiled f32 GEMM, 64x64 tile, 256 thr ----------------
template<int MODE>
__global__ __launch_bounds__(256) void gemm64_kernel(const float* __restrict__ A,
    const float* __restrict__ W, float* __restrict__ out0, float* __restrict__ out1,
    int M, int N, int K){
  __shared__ float AsT[32][68];
  __shared__ float Bs[32][64];
  int tid = threadIdx.x;
  int tx = tid & 15, ty = tid >> 4;
  int rowBase = blockIdx.x * 64, colBase = blockIdx.y * 64;
  float acc[4][4] = {};
  for (int kc = 0; kc < K; kc += 32){
    #pragma unroll
    for (int i = 0; i < 8; ++i){
      int idx = tid + i*256;
      int r = idx >> 5, k = idx & 31;
      AsT[k][r] = A[(size_t)(rowBase + r)*K + kc + k];
    }
    #pragma unroll
    for (int i = 0; i < 8; ++i){
      int idx = tid + i*256;
      int k = idx >> 6, c = idx & 63;
      Bs[k][c] = W[(size_t)(kc + k)*N + colBase + c];
    }
    __syncthreads();
    #pragma unroll
    for (int k = 0; k < 32; ++k){
      float4 a  = *(const float4*)&AsT[k][ty*4];
      float4 bv = *(const float4*)&Bs[k][tx*4];
      float av[4] = {a.x, a.y, a.z, a.w};
      float bb[4] = {bv.x, bv.y, bv.z, bv.w};
      #pragma unroll
      for (int ii = 0; ii < 4; ++ii)
        #pragma unroll
        for (int jj = 0; jj < 4; ++jj) acc[ii][jj] += av[ii]*bb[jj];
    }
    __syncthreads();
  }
  #pragma unroll
  for (int ii = 0; ii < 4; ++ii){
    int row = rowBase + ty*4 + ii;
    #pragma unroll
    for (int jj = 0; jj < 4; ++jj){
      int col = colBase + tx*4 + jj;
      float v = acc[ii][jj];
      if (MODE == 0){
        out0[(size_t)row*N + col] = v;
      } else {
        if (col < DI) out0[(size_t)row*DI + col] = v;
        else          out1[(size_t)row*DI + col - DI] = silu_f(v);
      }
    }
  }
}

// ---------------- 4. depthwise causal conv + silu ----------------
__global__ void conv_kernel(const float* __restrict__ xi_raw, const float* __restrict__ conv_w,
                            const float* __restrict__ conv_b, float* __restrict__ xi2){
  int row = blockIdx.x, d = threadIdx.x;
  int l = row & 511;
  float acc = conv_b[d];
  #pragma unroll
  for (int k = 0; k < 4; ++k){
    int t = l + k - 3;
    if (t >= 0) acc += xi_raw[(size_t)(row + k - 3)*DI + d] * conv_w[d*4 + k];
  }
  xi2[(size_t)row*DI + d] = silu_f(acc);
}

// ---------------- 5. dbl = xi2 @ x_proj_w, split outputs dbl8 / Bpack / Cpack ----------------
__global__ __launch_bounds__(256) void dbl_kernel(const float* __restrict__ xi2,
    const float* __restrict__ xpw, float* __restrict__ dbl8,
    float* __restrict__ Bpack, float* __restrict__ Cpack){
  __shared__ float Xs[64][65];
  __shared__ float Ws[64][48];
  int t = threadIdx.x;
  int r = t >> 2, g = t & 3;
  int rowBase = blockIdx.x * 64;
  float acc[12] = {};
  for (int kc = 0; kc < DI; kc += 64){
    #pragma unroll
    for (int i = 0; i < 16; ++i){
      int idx = t + i*256;
      int rr = idx >> 6, k = idx & 63;
      Xs[k][rr] = xi2[(size_t)(rowBase + rr)*DI + kc + k];
    }
    #pragma unroll
    for (int i = 0; i < 12; ++i){
      int idx = t + i*256;
      int k = idx / 48, j = idx % 48;
      Ws[k][j] = (j < 40) ? xpw[(kc + k)*40 + j] : 0.f;
    }
    __syncthreads();
    for (int k = 0; k < 64; ++k){
      float a = Xs[k][r];
      const float4* wr = (const float4*)&Ws[k][g*12];
      float4 w0 = wr[0], w1 = wr[1], w2 = wr[2];
      acc[0]  += a*w0.x; acc[1]  += a*w0.y; acc[2]  += a*w0.z; acc[3]  += a*w0.w;
      acc[4]  += a*w1.x; acc[5]  += a*w1.y; acc[6]  += a*w1.z; acc[7]  += a*w1.w;
      acc[8]  += a*w2.x; acc[9]  += a*w2.y; acc[10] += a*w2.z; acc[11] += a*w2.w;
    }
    __syncthreads();
  }
  size_t row = rowBase + r;
  #pragma unroll
  for (int jj = 0; jj < 12; ++jj){
    int j = g*12 + jj;
    if (j < 8)       dbl8[row*8 + j] = acc[jj];
    else if (j < 24) Bpack[row*16 + (j - 8)]  = acc[jj];
    else if (j < 40) Cpack[row*16 + (j - 24)] = acc[jj];
  }
}

// ---------------- 5b. dt precompute ----------------
__global__ __launch_bounds__(256) void dt_kernel(const float* __restrict__ dbl8,
    const float* __restrict__ dt_w, const float* __restrict__ dt_b,
    float* __restrict__ dtpre){
  __shared__ float rowp[8];
  int row = blockIdx.x, t = threadIdx.x;
  if (t < 8) rowp[t] = dbl8[(size_t)row*8 + t];
  __syncthreads();
  float dtp = dt_b[t];
  #pragma unroll
  for (int r = 0; r < 8; ++r) dtp += rowp[r] * dt_w[r*DI + t];
  float dt = fmaxf(dtp, 0.f) + log1pf(expf(-fabsf(dtp)));
  dtpre[(size_t)row*DI + t] = dt;
}

// ---------------- 6a. chunk-local scan (software-pipelined) ----------------
// grid (BB, DI/16, NC), block 256 = 16 d x 16 n
__global__ __launch_bounds__(256) void scan_part1_kernel(const float* __restrict__ dtpre,
    const float* __restrict__ xi2, const float* __restrict__ Bpack,
    const float* __restrict__ A_log, float* __restrict__ hend, float* __restrict__ Pprod){
  int t = threadIdx.x;
  int n = t & 15, dl = t >> 4;
  int d = blockIdx.y * 16 + dl;
  int b = blockIdx.x, j = blockIdx.z;
  float A = -expf(A_log[d*DSN + n]);
  float h = 0.f, dtsum = 0.f;
  const size_t row0 = (size_t)b * LL + (size_t)j * CL;
  const float* pdt = dtpre + row0*DI + d;
  const float* pB  = Bpack + row0*DSN + n;
  const float* pxi = xi2   + row0*DI + d;

  float dtA[4], BvA[4], xiA[4];
  float dtB[4], BvB[4], xiB[4];
  #pragma unroll
  for (int i = 0; i < 4; ++i){ dtA[i]=pdt[i*DI]; BvA[i]=pB[i*DSN]; xiA[i]=pxi[i*DI]; }
  #pragma unroll
  for (int g = 0; g < CL/8; ++g){
    const int s1 = g*8 + 4;
    #pragma unroll
    for (int i = 0; i < 4; ++i){ dtB[i]=pdt[(s1+i)*DI]; BvB[i]=pB[(s1+i)*DSN]; xiB[i]=pxi[(s1+i)*DI]; }
    #pragma unroll
    for (int i = 0; i < 4; ++i){
      float dA = expf(dtA[i]*A);
      h = dA*h + (dtA[i]*xiA[i])*BvA[i];
      dtsum += dtA[i];
    }
    const int s2 = g*8 + 8;
    if (g < CL/8 - 1){
      #pragma unroll
      for (int i = 0; i < 4; ++i){ dtA[i]=pdt[(s2+i)*DI]; BvA[i]=pB[(s2+i)*DSN]; xiA[i]=pxi[(s2+i)*DI]; }
    }
    #pragma unroll
    for (int i = 0; i < 4; ++i){
      float dA = expf(dtB[i]*A);
      h = dA*h + (dtB[i]*xiB[i])*BvB[i];
      dtsum += dtB[i];
    }
  }
  size_t idx = (((size_t)b*DI + d)*DSN + n)*NC + j;
  hend[idx]  = h;
  Pprod[idx] = expf(A * dtsum);
}

// ---------------- 6b. carry scan across chunks (in-place: hend <- carry-in) ----------------
__global__ void carry_kernel(float* __restrict__ hend, const float* __restrict__ Pprod){
  int idx = blockIdx.x*256 + threadIdx.x;   // (b*DI+d)*DSN+n
  size_t base = (size_t)idx * NC;
  float c = 0.f;
  #pragma unroll
  for (int j = 0; j < NC; ++j){
    float he = hend[base + j];
    float P  = Pprod[base + j];
    hend[base + j] = c;       // carry-in for chunk j
    c = P * c + he;
  }
}

// ---------------- 6c. final scan per chunk from carry-in (software-pipelined) ----------------
__global__ __launch_bounds__(256) void scan_part2_kernel(const float* __restrict__ dtpre,
    const float* __restrict__ xi2, const float* __restrict__ zbuf,
    const float* __restrict__ Bpack, const float* __restrict__ Cpack,
    const float* __restrict__ A_log, const float* __restrict__ Dp,
    const float* __restrict__ cin, float* __restrict__ ybuf){
  int t = threadIdx.x;
  int n = t & 15, dl = t >> 4;
  int d = blockIdx.y * 16 + dl;
  int b = blockIdx.x, j = blockIdx.z;
  float A = -expf(A_log[d*DSN + n]);
  float Dd = Dp[d];
  float h = cin[(((size_t)b*DI + d)*DSN + n)*NC + j];
  const size_t row0 = (size_t)b * LL + (size_t)j * CL;
  const float* pdt = dtpre + row0*DI + d;
  const float* pB  = Bpack + row0*DSN + n;
  const float* pC  = Cpack + row0*DSN + n;
  const float* pxi = xi2   + row0*DI + d;
  const float* pz  = zbuf  + row0*DI + d;
  float* py = ybuf + row0*DI + d;

  float dtA[4], BvA[4], CvA[4], xiA[4], zA[4];
  float dtB[4], BvB[4], CvB[4], xiB[4], zB[4];
  #pragma unroll
  for (int i = 0; i < 4; ++i){
    dtA[i]=pdt[i*DI]; BvA[i]=pB[i*DSN]; CvA[i]=pC[i*DSN]; xiA[i]=pxi[i*DI]; zA[i]=pz[i*DI];
  }
  #pragma unroll
  for (int g = 0; g < CL/8; ++g){
    const int s1 = g*8 + 4;
    #pragma unroll
    for (int i = 0; i < 4; ++i){
      dtB[i]=pdt[(s1+i)*DI]; BvB[i]=pB[(s1+i)*DSN]; CvB[i]=pC[(s1+i)*DSN];
      xiB[i]=pxi[(s1+i)*DI]; zB[i]=pz[(s1+i)*DI];
    }
    #pragma unroll
    for (int i = 0; i < 4; ++i){
      float dA = expf(dtA[i]*A);
      h = dA*h + (dtA[i]*xiA[i])*BvA[i];
      float p = h * CvA[i];
      p += __shfl_xor(p, 8, 16);
      p += __shfl_xor(p, 4, 16);
      p += __shfl_xor(p, 2, 16);
      p += __shfl_xor(p, 1, 16);
      if (n == 0) py[(g*8 + i)*DI] = (p + Dd*xiA[i]) * zA[i];
    }
    const int s2 = g*8 + 8;
    if (g < CL/8 - 1){
      #pragma unroll
      for (int i = 0; i < 4; ++i){
        dtA[i]=pdt[(s2+i)*DI]; BvA[i]=pB[(s2+i)*DSN]; CvA[i]=pC[(s2+i)*DSN];
        xiA[i]=pxi[(s2+i)*DI]; zA[i]=pz[(s2+i)*DI];
      }
    }
    #pragma unroll
    for (int i = 0; i < 4; ++i){
      float dA = expf(dtB[i]*A);
      h = dA*h + (dtB[i]*xiB[i])*BvB[i];
      float p = h * CvB[i];
      p += __shfl_xor(p, 8, 16);
      p += __shfl_xor(p, 4, 16);
      p += __shfl_xor(p, 2, 16);
      p += __shfl_xor(p, 1, 16);
      if (n == 0) py[(s1 + i)*DI] = (p + Dd*xiB[i]) * zB[i];
    }
  }
}

// ---------------- 8. out_layer dot + denorm + fc0 ----------------
__global__ void outlayer_kernel(const float* __restrict__ yout, const float* __restrict__ olw,
                                const float* __restrict__ stats, const float* __restrict__ fc0w,
                                const float* __restrict__ fc0b, float* __restrict__ h0){
  __shared__ float red[2];
  int row = blockIdx.x, t = threadIdx.x;   // 128 threads
  float v = yout[(size_t)row*DM + t] * olw[t];
  #pragma unroll
  for (int off = 32; off; off >>= 1) v += __shfl_down(v, off);
  if ((t & 63) == 0) red[t >> 6] = v;
  __syncthreads();
  if (t == 0){
    int b = row >> 9;
    float s = red[0] + red[1];
    float xo = s * stats[BB + b] + stats[b];
    float dec = fmaxf(xo, 0.f);
    h0[row] = fmaxf(dec * fc0w[0] + fc0b[0], 0.f);
  }
}

// ---------------- 9. final MLP per batch ----------------
__global__ __launch_bounds__(128) void mlp_kernel(const float* __restrict__ h0,
    const float* __restrict__ fc1w, const float* __restrict__ fc1b,
    const float* __restrict__ fc2w, const float* __restrict__ fc2b,
    const float* __restrict__ fc3w, const float* __restrict__ fc3b,
    float* __restrict__ out){
  __shared__ float h0s[LL];
  __shared__ float h1s[128];
  __shared__ float h2s[64];
  int b = blockIdx.x, t = threadIdx.x;
  #pragma unroll
  for (int i = 0; i < 4; ++i) h0s[t + i*128] = h0[b*LL + t + i*128];
  __syncthreads();
  float a = fc1b[t];
  for (int l = 0; l < LL; ++l) a += h0s[l] * fc1w[l*128 + t];
  h1s[t] = fmaxf(a, 0.f);
  __syncthreads();
  if (t < 64){
    float a2 = fc2b[t];
    #pragma unroll 4
    for (int k = 0; k < 128; ++k) a2 += h1s[k] * fc2w[k*64 + t];
    h2s[t] = fmaxf(a2, 0.f);
  }
  __syncthreads();
  if (t < 64){
    float p = h2s[t] * fc3w[t];
    #pragma unroll
    for (int off = 32; off; off >>= 1) p += __shfl_down(p, off);
    if (t == 0) out[b] = p + fc3b[0];
  }
}

extern "C" void kernel_launch(void* const* d_in, const int* in_sizes, int n_in,
                              void* d_out, int out_size, void* d_ws, size_t ws_size,
                              hipStream_t stream){
  const float* x_enc      = (const float*)d_in[0];
  const float* x_mark_enc = (const float*)d_in[1];
  const float* tok_w      = (const float*)d_in[4];
  const float* temp_w     = (const float*)d_in[5];
  const float* in_proj_w  = (const float*)d_in[6];
  const float* conv_w     = (const float*)d_in[7];
  const float* conv_b     = (const float*)d_in[8];
  const float* x_proj_w   = (const float*)d_in[9];
  const float* dt_w       = (const float*)d_in[10];
  const float* dt_b       = (const float*)d_in[11];
  const float* A_log      = (const float*)d_in[12];
  const float* Dp         = (const float*)d_in[13];
  const float* out_proj_w = (const float*)d_in[14];
  const float* out_lay_w  = (const float*)d_in[15];
  const float* fc0_w      = (const float*)d_in[16];
  const float* fc0_b      = (const float*)d_in[17];
  const float* fc1_w      = (const float*)d_in[18];
  const float* fc1_b      = (const float*)d_in[19];
  const float* fc2_w      = (const float*)d_in[20];
  const float* fc2_b      = (const float*)d_in[21];
  const float* fc3_w      = (const float*)d_in[22];
  const float* fc3_b      = (const float*)d_in[23];
  float* outp = (float*)d_out;

  float* ws = (float*)d_ws;
  const int M = BB*LL;
  float* xn     = ws;                                   // M
  float* stats  = xn + M;                               // 64
  float* xbuf   = stats + 64;                           // M*128 (8MB)
  float* xi_raw = xbuf + (size_t)M*DM;                  // M*256
  float* zbuf   = xi_raw + (size_t)M*DI;                // M*256
  float* xi2    = zbuf + (size_t)M*DI;                  // M*256
  float* dbl8   = xi2 + (size_t)M*DI;                   // M*8
  float* Bpack  = dbl8 + (size_t)M*8;                   // M*16
  float* Cpack  = Bpack + (size_t)M*16;                 // M*16
  float* dtpre  = Cpack + (size_t)M*16;                 // M*256
  float* h0     = dtpre + (size_t)M*DI;                 // M
  float* ybuf   = xi_raw;                               // reuse (dead after conv)
  float* yout   = xbuf;                                 // reuse (dead after scan)
  // hend/Pprod live in xbuf (dead between in_proj gemm and out_proj gemm)
  float* hend   = xbuf;
  float* Pprod  = xbuf + (size_t)BB*DI*DSN*NC;

  norm_kernel<<<BB, 256, 0, stream>>>(x_enc, xn, stats);
  embed_kernel<<<M, DM, 0, stream>>>(xn, x_mark_enc, tok_w, temp_w, xbuf);
  gemm64_kernel<1><<<dim3(M/64, 8), 256, 0, stream>>>(xbuf, in_proj_w, xi_raw, zbuf, M, 512, DM);
  conv_kernel<<<M, DI, 0, stream>>>(xi_raw, conv_w, conv_b, xi2);
  dbl_kernel<<<M/64, 256, 0, stream>>>(xi2, x_proj_w, dbl8, Bpack, Cpack);
  dt_kernel<<<M, DI, 0, stream>>>(dbl8, dt_w, dt_b, dtpre);
  scan_part1_kernel<<<dim3(BB, DI/16, NC), 256, 0, stream>>>(dtpre, xi2, Bpack, A_log, hend, Pprod);
  carry_kernel<<<BB*DI*DSN/256, 256, 0, stream>>>(hend, Pprod);
  scan_part2_kernel<<<dim3(BB, DI/16, NC), 256, 0, stream>>>(dtpre, xi2, zbuf, Bpack, Cpack, A_log, Dp, hend, ybuf);
  gemm64_kernel<0><<<dim3(M/64, 2), 256, 0, stream>>>(ybuf, out_proj_w, yout, nullptr, M, DM, DI);
  outlayer_kernel<<<M, DM, 0, stream>>>(yout, out_lay_w, stats, fc0_w, fc0_b, h0);
  mlp_kernel<<<BB, 128, 0, stream>>>(h0, fc1_w, fc1_b, fc2_w, fc2_b, fc3_w, fc3_b, outp);
}

// Round 5
// 282.124 us; speedup vs baseline: 2.9405x; 1.0110x over previous
//
#include <hip/hip_runtime.h>
#include <math.h>

#define BB 32
#define LL 512
#define DM 128
#define DI 256
#define DSN 16
#define NMK 4
#define NC 8
#define CL 64   // LL/NC

__device__ __forceinline__ float silu_f(float x){ return x / (1.f + __expf(-x)); }

// ---------------- 1. per-batch normalization ----------------
__global__ void norm_kernel(const float* __restrict__ x_enc,
                            float* __restrict__ xn, float* __restrict__ stats){
  __shared__ float xs[LL];
  __shared__ float red[256];
  int b = blockIdx.x, t = threadIdx.x;
  xs[t]       = x_enc[b*LL + t];
  xs[t + 256] = x_enc[b*LL + t + 256];
  __syncthreads();
  red[t] = xs[t] + xs[t + 256];
  __syncthreads();
  for (int s = 128; s; s >>= 1){ if (t < s) red[t] += red[t + s]; __syncthreads(); }
  float mean = red[0] / (float)LL;
  __syncthreads();
  float xc0 = xs[t] - mean, xc1 = xs[t + 256] - mean;
  red[t] = xc0*xc0 + xc1*xc1;
  __syncthreads();
  for (int s = 128; s; s >>= 1){ if (t < s) red[t] += red[t + s]; __syncthreads(); }
  float var = red[0] / (float)LL;
  float sd = sqrtf(var + 1e-5f);
  xn[b*LL + t]       = xc0 / sd;
  xn[b*LL + t + 256] = xc1 / sd;
  if (t == 0){ stats[b] = mean; stats[BB + b] = sd; }
}

// ---------------- 2. token conv + temporal + positional embedding ----------------
__global__ void embed_kernel(const float* __restrict__ xn, const float* __restrict__ xmark,
                             const float* __restrict__ tok_w, const float* __restrict__ temp_w,
                             float* __restrict__ xbuf){
  int row = blockIdx.x;          // b*LL + l
  int o = threadIdx.x;           // 0..127
  int b = row >> 9, l = row & 511;
  float xm1 = xn[b*LL + ((l == 0) ? (LL - 1) : (l - 1))];
  float x0  = xn[row];
  float xp1 = xn[b*LL + ((l == LL - 1) ? 0 : (l + 1))];
  float v = xm1 * tok_w[o*3 + 0] + x0 * tok_w[o*3 + 1] + xp1 * tok_w[o*3 + 2];
  #pragma unroll
  for (int m = 0; m < NMK; ++m) v += xmark[row*NMK + m] * temp_w[m*DM + o];
  int i = o >> 1;
  float ang = (float)l * expf((float)(2*i) * -0.07195578415606394f); // -ln(10000)/128
  v += (o & 1) ? cosf(ang) : sinf(ang);
  xbuf[row*DM + o] = v;
}

// ---------------- 3. in_proj GEMM 64x64 tile; epilogue splits xi / silu(z) ----------------
template<int MODE>
__global__ __launch_bounds__(256) void gemm64_kernel(const float* __restrict__ A,
    const float* __restrict__ W, float* __restrict__ out0, float* __restrict__ out1,
    int M, int N, int K){
  __shared__ float AsT[32][68];
  __shared__ float Bs[32][64];
  int tid = threadIdx.x;
  int tx = tid & 15, ty = tid >> 4;
  int rowBase = blockIdx.x * 64, colBase = blockIdx.y * 64;
  float acc[4][4] = {};
  for (int kc = 0; kc < K; kc += 32){
    #pragma unroll
    for (int i = 0; i < 8; ++i){
      int idx = tid + i*256;
      int r = idx >> 5, k = idx & 31;
      AsT[k][r] = A[(size_t)(rowBase + r)*K + kc + k];
    }
    #pragma unroll
    for (int i = 0; i < 8; ++i){
      int idx = tid + i*256;
      int k = idx >> 6, c = idx & 63;
      Bs[k][c] = W[(size_t)(kc + k)*N + colBase + c];
    }
    __syncthreads();
    #pragma unroll
    for (int k = 0; k < 32; ++k){
      float4 a  = *(const float4*)&AsT[k][ty*4];
      float4 bv = *(const float4*)&Bs[k][tx*4];
      float av[4] = {a.x, a.y, a.z, a.w};
      float bb[4] = {bv.x, bv.y, bv.z, bv.w};
      #pragma unroll
      for (int ii = 0; ii < 4; ++ii)
        #pragma unroll
        for (int jj = 0; jj < 4; ++jj) acc[ii][jj] += av[ii]*bb[jj];
    }
    __syncthreads();
  }
  #pragma unroll
  for (int ii = 0; ii < 4; ++ii){
    int row = rowBase + ty*4 + ii;
    #pragma unroll
    for (int jj = 0; jj < 4; ++jj){
      int col = colBase + tx*4 + jj;
      float v = acc[ii][jj];
      if (MODE == 0){
        out0[(size_t)row*N + col] = v;
      } else {
        if (col < DI) out0[(size_t)row*DI + col] = v;
        else          out1[(size_t)row*DI + col - DI] = silu_f(v);
      }
    }
  }
}

// ---------------- 4. depthwise causal conv + silu ----------------
__global__ void conv_kernel(const float* __restrict__ xi_raw, const float* __restrict__ conv_w,
                            const float* __restrict__ conv_b, float* __restrict__ xi2){
  int row = blockIdx.x, d = threadIdx.x;
  int l = row & 511;
  float acc = conv_b[d];
  #pragma unroll
  for (int k = 0; k < 4; ++k){
    int t = l + k - 3;
    if (t >= 0) acc += xi_raw[(size_t)(row + k - 3)*DI + d] * conv_w[d*4 + k];
  }
  xi2[(size_t)row*DI + d] = silu_f(acc);
}

// ---------------- 5. dbl GEMM (N=40) + fused dt projection/softplus ----------------
__global__ __launch_bounds__(256) void dbl_kernel(const float* __restrict__ xi2,
    const float* __restrict__ xpw, const float* __restrict__ dt_w,
    const float* __restrict__ dt_b, float* __restrict__ Bpack,
    float* __restrict__ Cpack, float* __restrict__ dtpre){
  __shared__ float Xs[64][65];
  __shared__ float Ws[64][48];
  __shared__ float rowp8[64][8];
  int t = threadIdx.x;
  int r = t >> 2, g = t & 3;
  int rowBase = blockIdx.x * 64;
  float acc[12] = {};
  for (int kc = 0; kc < DI; kc += 64){
    #pragma unroll
    for (int i = 0; i < 16; ++i){
      int idx = t + i*256;
      int rr = idx >> 6, k = idx & 63;
      Xs[k][rr] = xi2[(size_t)(rowBase + rr)*DI + kc + k];
    }
    #pragma unroll
    for (int i = 0; i < 12; ++i){
      int idx = t + i*256;
      int k = idx / 48, j = idx % 48;
      Ws[k][j] = (j < 40) ? xpw[(kc + k)*40 + j] : 0.f;
    }
    __syncthreads();
    for (int k = 0; k < 64; ++k){
      float a = Xs[k][r];
      const float4* wr = (const float4*)&Ws[k][g*12];
      float4 w0 = wr[0], w1 = wr[1], w2 = wr[2];
      acc[0]  += a*w0.x; acc[1]  += a*w0.y; acc[2]  += a*w0.z; acc[3]  += a*w0.w;
      acc[4]  += a*w1.x; acc[5]  += a*w1.y; acc[6]  += a*w1.z; acc[7]  += a*w1.w;
      acc[8]  += a*w2.x; acc[9]  += a*w2.y; acc[10] += a*w2.z; acc[11] += a*w2.w;
    }
    __syncthreads();
  }
  size_t row = rowBase + r;
  #pragma unroll
  for (int jj = 0; jj < 12; ++jj){
    int j = g*12 + jj;
    if (j >= 8 && j < 24)  Bpack[row*16 + (j - 8)]  = acc[jj];
    else if (j >= 24)      Cpack[row*16 + (j - 24)] = acc[jj];
  }
  if (g == 0){
    #pragma unroll
    for (int jj = 0; jj < 8; ++jj) rowp8[r][jj] = acc[jj];
  }
  __syncthreads();
  // dt phase: thread t = channel d; 64 rows each
  float dtw_l[8];
  #pragma unroll
  for (int q = 0; q < 8; ++q) dtw_l[q] = dt_w[q*DI + t];
  float dtb_l = dt_b[t];
  for (int rr = 0; rr < 64; ++rr){
    float dtp = dtb_l;
    #pragma unroll
    for (int q = 0; q < 8; ++q) dtp += rowp8[rr][q] * dtw_l[q];
    float dt = fmaxf(dtp, 0.f) + log1pf(__expf(-fabsf(dtp)));
    dtpre[(size_t)(rowBase + rr)*DI + t] = dt;
  }
}

// ---------------- 6a. chunk-local scan (pipelined, native exp) ----------------
__global__ __launch_bounds__(256) void scan_part1_kernel(const float* __restrict__ dtpre,
    const float* __restrict__ xi2, const float* __restrict__ Bpack,
    const float* __restrict__ A_log, float* __restrict__ hend, float* __restrict__ Pprod){
  int t = threadIdx.x;
  int n = t & 15, dl = t >> 4;
  int d = blockIdx.y * 16 + dl;
  int b = blockIdx.x, j = blockIdx.z;
  float A = -__expf(A_log[d*DSN + n]);
  float h = 0.f, dtsum = 0.f;
  const size_t row0 = (size_t)b * LL + (size_t)j * CL;
  const float* pdt = dtpre + row0*DI + d;
  const float* pB  = Bpack + row0*DSN + n;
  const float* pxi = xi2   + row0*DI + d;

  float dtA[4], BvA[4], xiA[4];
  float dtB[4], BvB[4], xiB[4];
  #pragma unroll
  for (int i = 0; i < 4; ++i){ dtA[i]=pdt[i*DI]; BvA[i]=pB[i*DSN]; xiA[i]=pxi[i*DI]; }
  pdt += 4*DI; pB += 4*DSN; pxi += 4*DI;
  #pragma unroll
  for (int g = 0; g < CL/8; ++g){
    #pragma unroll
    for (int i = 0; i < 4; ++i){ dtB[i]=pdt[i*DI]; BvB[i]=pB[i*DSN]; xiB[i]=pxi[i*DI]; }
    pdt += 4*DI; pB += 4*DSN; pxi += 4*DI;
    #pragma unroll
    for (int i = 0; i < 4; ++i){
      float dA = __expf(dtA[i]*A);
      h = dA*h + (dtA[i]*xiA[i])*BvA[i];
      dtsum += dtA[i];
    }
    if (g < CL/8 - 1){
      #pragma unroll
      for (int i = 0; i < 4; ++i){ dtA[i]=pdt[i*DI]; BvA[i]=pB[i*DSN]; xiA[i]=pxi[i*DI]; }
      pdt += 4*DI; pB += 4*DSN; pxi += 4*DI;
    }
    #pragma unroll
    for (int i = 0; i < 4; ++i){
      float dA = __expf(dtB[i]*A);
      h = dA*h + (dtB[i]*xiB[i])*BvB[i];
      dtsum += dtB[i];
    }
  }
  size_t idx = (((size_t)b*DI + d)*DSN + n)*NC + j;
  hend[idx]  = h;
  Pprod[idx] = __expf(A * dtsum);
}

// ---------------- 6b. final scan per chunk, carry computed inline ----------------
__global__ __launch_bounds__(256) void scan_part2_kernel(const float* __restrict__ dtpre,
    const float* __restrict__ xi2, const float* __restrict__ zbuf,
    const float* __restrict__ Bpack, const float* __restrict__ Cpack,
    const float* __restrict__ A_log, const float* __restrict__ Dp,
    const float* __restrict__ hend, const float* __restrict__ Pprod,
    float* __restrict__ ybuf){
  int t = threadIdx.x;
  int n = t & 15, dl = t >> 4;
  int d = blockIdx.y * 16 + dl;
  int b = blockIdx.x, j = blockIdx.z;
  float A = -__expf(A_log[d*DSN + n]);
  float Dd = Dp[d];
  // inline carry over previous chunks
  size_t cb = (((size_t)b*DI + d)*DSN + n)*NC;
  float h = 0.f;
  for (int jj = 0; jj < j; ++jj) h = Pprod[cb + jj]*h + hend[cb + jj];

  const size_t row0 = (size_t)b * LL + (size_t)j * CL;
  const float* pdt = dtpre + row0*DI + d;
  const float* pB  = Bpack + row0*DSN + n;
  const float* pC  = Cpack + row0*DSN + n;
  const float* pxi = xi2   + row0*DI + d;
  const float* pz  = zbuf  + row0*DI + d;
  float* py = ybuf + row0*DI + d;

  float dtA[4], BvA[4], CvA[4], xiA[4], zA[4];
  float dtB[4], BvB[4], CvB[4], xiB[4], zB[4];
  #pragma unroll
  for (int i = 0; i < 4; ++i){
    dtA[i]=pdt[i*DI]; BvA[i]=pB[i*DSN]; CvA[i]=pC[i*DSN]; xiA[i]=pxi[i*DI]; zA[i]=pz[i*DI];
  }
  pdt += 4*DI; pB += 4*DSN; pC += 4*DSN; pxi += 4*DI; pz += 4*DI;
  #pragma unroll
  for (int g = 0; g < CL/8; ++g){
    #pragma unroll
    for (int i = 0; i < 4; ++i){
      dtB[i]=pdt[i*DI]; BvB[i]=pB[i*DSN]; CvB[i]=pC[i*DSN]; xiB[i]=pxi[i*DI]; zB[i]=pz[i*DI];
    }
    pdt += 4*DI; pB += 4*DSN; pC += 4*DSN; pxi += 4*DI; pz += 4*DI;
    #pragma unroll
    for (int i = 0; i < 4; ++i){
      float dA = __expf(dtA[i]*A);
      h = dA*h + (dtA[i]*xiA[i])*BvA[i];
      float p = h * CvA[i];
      p += __shfl_xor(p, 8, 16);
      p += __shfl_xor(p, 4, 16);
      p += __shfl_xor(p, 2, 16);
      p += __shfl_xor(p, 1, 16);
      if (n == 0) py[i*DI] = (p + Dd*xiA[i]) * zA[i];
    }
    py += 4*DI;
    if (g < CL/8 - 1){
      #pragma unroll
      for (int i = 0; i < 4; ++i){
        dtA[i]=pdt[i*DI]; BvA[i]=pB[i*DSN]; CvA[i]=pC[i*DSN]; xiA[i]=pxi[i*DI]; zA[i]=pz[i*DI];
      }
      pdt += 4*DI; pB += 4*DSN; pC += 4*DSN; pxi += 4*DI; pz += 4*DI;
    }
    #pragma unroll
    for (int i = 0; i < 4; ++i){
      float dA = __expf(dtB[i]*A);
      h = dA*h + (dtB[i]*xiB[i])*BvB[i];
      float p = h * CvB[i];
      p += __shfl_xor(p, 8, 16);
      p += __shfl_xor(p, 4, 16);
      p += __shfl_xor(p, 2, 16);
      p += __shfl_xor(p, 1, 16);
      if (n == 0) py[i*DI] = (p + Dd*xiB[i]) * zB[i];
    }
    py += 4*DI;
  }
}

// ---------------- 7. out_proj GEMM (64x128 tile) + fused outlayer/denorm/fc0 ----------------
__global__ __launch_bounds__(256) void gemm_out_kernel(const float* __restrict__ A,
    const float* __restrict__ W, const float* __restrict__ olw,
    const float* __restrict__ stats, const float* __restrict__ fc0w,
    const float* __restrict__ fc0b, float* __restrict__ h0){
  __shared__ float AsT[32][68];
  __shared__ float Bs[32][128];
  int tid = threadIdx.x;
  int tx = tid & 15, ty = tid >> 4;
  int rowBase = blockIdx.x * 64;
  float acc[4][8] = {};
  for (int kc = 0; kc < DI; kc += 32){
    #pragma unroll
    for (int i = 0; i < 8; ++i){
      int idx = tid + i*256;
      int r = idx >> 5, k = idx & 31;
      AsT[k][r] = A[(size_t)(rowBase + r)*DI + kc + k];
    }
    #pragma unroll
    for (int i = 0; i < 16; ++i){
      int idx = tid + i*256;
      int k = idx >> 7, c = idx & 127;
      Bs[k][c] = W[(size_t)(kc + k)*DM + c];
    }
    __syncthreads();
    #pragma unroll
    for (int k = 0; k < 32; ++k){
      float4 a  = *(const float4*)&AsT[k][ty*4];
      float4 b0 = *(const float4*)&Bs[k][tx*4];
      float4 b1 = *(const float4*)&Bs[k][64 + tx*4];
      float av[4] = {a.x, a.y, a.z, a.w};
      float b0v[4] = {b0.x, b0.y, b0.z, b0.w};
      float b1v[4] = {b1.x, b1.y, b1.z, b1.w};
      #pragma unroll
      for (int ii = 0; ii < 4; ++ii){
        #pragma unroll
        for (int jj = 0; jj < 4; ++jj){
          acc[ii][jj]     += av[ii]*b0v[jj];
          acc[ii][jj + 4] += av[ii]*b1v[jj];
        }
      }
    }
    __syncthreads();
  }
  // epilogue: s = row . olw ; xo = s*sd+mean ; h0 = relu(relu(xo)*fc0w+fc0b)
  float w0[4], w1[4];
  #pragma unroll
  for (int q = 0; q < 4; ++q){ w0[q] = olw[tx*4 + q]; w1[q] = olw[64 + tx*4 + q]; }
  int b = rowBase >> 9;
  float mean = stats[b], sd = stats[BB + b];
  float f0w = fc0w[0], f0b = fc0b[0];
  #pragma unroll
  for (int ii = 0; ii < 4; ++ii){
    float s = 0.f;
    #pragma unroll
    for (int q = 0; q < 4; ++q) s += acc[ii][q]*w0[q] + acc[ii][q + 4]*w1[q];
    s += __shfl_xor(s, 8, 16);
    s += __shfl_xor(s, 4, 16);
    s += __shfl_xor(s, 2, 16);
    s += __shfl_xor(s, 1, 16);
    if (tx == 0){
      float xo = s*sd + mean;
      float dec = fmaxf(xo, 0.f);
      h0[rowBase + ty*4 + ii] = fmaxf(dec*f0w + f0b, 0.f);
    }
  }
}

// ---------------- 9. final MLP per batch ----------------
__global__ __launch_bounds__(128) void mlp_kernel(const float* __restrict__ h0,
    const float* __restrict__ fc1w, const float* __restrict__ fc1b,
    const float* __restrict__ fc2w, const float* __restrict__ fc2b,
    const float* __restrict__ fc3w, const float* __restrict__ fc3b,
    float* __restrict__ out){
  __shared__ float h0s[LL];
  __shared__ float h1s[128];
  __shared__ float h2s[64];
  int b = blockIdx.x, t = threadIdx.x;
  #pragma unroll
  for (int i = 0; i < 4; ++i) h0s[t + i*128] = h0[b*LL + t + i*128];
  __syncthreads();
  float a = fc1b[t];
  for (int l = 0; l < LL; ++l) a += h0s[l] * fc1w[l*128 + t];
  h1s[t] = fmaxf(a, 0.f);
  __syncthreads();
  if (t < 64){
    float a2 = fc2b[t];
    #pragma unroll 4
    for (int k = 0; k < 128; ++k) a2 += h1s[k] * fc2w[k*64 + t];
    h2s[t] = fmaxf(a2, 0.f);
  }
  __syncthreads();
  if (t < 64){
    float p = h2s[t] * fc3w[t];
    #pragma unroll
    for (int off = 32; off; off >>= 1) p += __shfl_down(p, off);
    if (t == 0) out[b] = p + fc3b[0];
  }
}

extern "C" void kernel_launch(void* const* d_in, const int* in_sizes, int n_in,
                              void* d_out, int out_size, void* d_ws, size_t ws_size,
                              hipStream_t stream){
  const float* x_enc      = (const float*)d_in[0];
  const float* x_mark_enc = (const float*)d_in[1];
  const float* tok_w      = (const float*)d_in[4];
  const float* temp_w     = (const float*)d_in[5];
  const float* in_proj_w  = (const float*)d_in[6];
  const float* conv_w     = (const float*)d_in[7];
  const float* conv_b     = (const float*)d_in[8];
  const float* x_proj_w   = (const float*)d_in[9];
  const float* dt_w       = (const float*)d_in[10];
  const float* dt_b       = (const float*)d_in[11];
  const float* A_log      = (const float*)d_in[12];
  const float* Dp         = (const float*)d_in[13];
  const float* out_proj_w = (const float*)d_in[14];
  const float* out_lay_w  = (const float*)d_in[15];
  const float* fc0_w      = (const float*)d_in[16];
  const float* fc0_b      = (const float*)d_in[17];
  const float* fc1_w      = (const float*)d_in[18];
  const float* fc1_b      = (const float*)d_in[19];
  const float* fc2_w      = (const float*)d_in[20];
  const float* fc2_b      = (const float*)d_in[21];
  const float* fc3_w      = (const float*)d_in[22];
  const float* fc3_b      = (const float*)d_in[23];
  float* outp = (float*)d_out;

  float* ws = (float*)d_ws;
  const int M = BB*LL;
  float* xn     = ws;                                   // M
  float* stats  = xn + M;                               // 64
  float* xbuf   = stats + 64;                           // M*128 (8MB)
  float* xi_raw = xbuf + (size_t)M*DM;                  // M*256
  float* zbuf   = xi_raw + (size_t)M*DI;                // M*256
  float* xi2    = zbuf + (size_t)M*DI;                  // M*256
  float* Bpack  = xi2 + (size_t)M*DI;                   // M*16
  float* Cpack  = Bpack + (size_t)M*16;                 // M*16
  float* dtpre  = Cpack + (size_t)M*16;                 // M*256
  float* h0     = dtpre + (size_t)M*DI;                 // M
  float* ybuf   = xi_raw;                               // reuse (dead after conv)
  // hend/Pprod live in xbuf (dead after in_proj gemm)
  float* hend   = xbuf;
  float* Pprod  = xbuf + (size_t)BB*DI*DSN*NC;

  norm_kernel<<<BB, 256, 0, stream>>>(x_enc, xn, stats);
  embed_kernel<<<M, DM, 0, stream>>>(xn, x_mark_enc, tok_w, temp_w, xbuf);
  gemm64_kernel<1><<<dim3(M/64, 8), 256, 0, stream>>>(xbuf, in_proj_w, xi_raw, zbuf, M, 512, DM);
  conv_kernel<<<M, DI, 0, stream>>>(xi_raw, conv_w, conv_b, xi2);
  dbl_kernel<<<M/64, 256, 0, stream>>>(xi2, x_proj_w, dt_w, dt_b, Bpack, Cpack, dtpre);
  scan_part1_kernel<<<dim3(BB, DI/16, NC), 256, 0, stream>>>(dtpre, xi2, Bpack, A_log, hend, Pprod);
  scan_part2_kernel<<<dim3(BB, DI/16, NC), 256, 0, stream>>>(dtpre, xi2, zbuf, Bpack, Cpack, A_log, Dp, hend, Pprod, ybuf);
  gemm_out_kernel<<<M/64, 256, 0, stream>>>(ybuf, out_proj_w, out_lay_w, stats, fc0_w, fc0_b, h0);
  mlp_kernel<<<BB, 128, 0, stream>>>(h0, fc1_w, fc1_b, fc2_w, fc2_b, fc3_w, fc3_b, outp);
}

// Round 6
// 255.555 us; speedup vs baseline: 3.2463x; 1.1040x over previous
//
#include <hip/hip_runtime.h>
#include <math.h>

#define BB 32
#define LL 512
#define DM 128
#define DI 256
#define DSN 16
#define NMK 4
#define NC 8
#define CL 64   // LL/NC

__device__ __forceinline__ float silu_f(float x){ return x / (1.f + __expf(-x)); }

// ---------------- 1. per-batch normalization ----------------
__global__ void norm_kernel(const float* __restrict__ x_enc,
                            float* __restrict__ xn, float* __restrict__ stats){
  __shared__ float xs[LL];
  __shared__ float red[256];
  int b = blockIdx.x, t = threadIdx.x;
  xs[t]       = x_enc[b*LL + t];
  xs[t + 256] = x_enc[b*LL + t + 256];
  __syncthreads();
  red[t] = xs[t] + xs[t + 256];
  __syncthreads();
  for (int s = 128; s; s >>= 1){ if (t < s) red[t] += red[t + s]; __syncthreads(); }
  float mean = red[0] / (float)LL;
  __syncthreads();
  float xc0 = xs[t] - mean, xc1 = xs[t + 256] - mean;
  red[t] = xc0*xc0 + xc1*xc1;
  __syncthreads();
  for (int s = 128; s; s >>= 1){ if (t < s) red[t] += red[t + s]; __syncthreads(); }
  float var = red[0] / (float)LL;
  float sd = sqrtf(var + 1e-5f);
  xn[b*LL + t]       = xc0 / sd;
  xn[b*LL + t + 256] = xc1 / sd;
  if (t == 0){ stats[b] = mean; stats[BB + b] = sd; }
}

// ---------------- 2. token conv + temporal + positional embedding ----------------
__global__ void embed_kernel(const float* __restrict__ xn, const float* __restrict__ xmark,
                             const float* __restrict__ tok_w, const float* __restrict__ temp_w,
                             float* __restrict__ xbuf){
  int row = blockIdx.x;          // b*LL + l
  int o = threadIdx.x;           // 0..127
  int b = row >> 9, l = row & 511;
  float xm1 = xn[b*LL + ((l == 0) ? (LL - 1) : (l - 1))];
  float x0  = xn[row];
  float xp1 = xn[b*LL + ((l == LL - 1) ? 0 : (l + 1))];
  float v = xm1 * tok_w[o*3 + 0] + x0 * tok_w[o*3 + 1] + xp1 * tok_w[o*3 + 2];
  #pragma unroll
  for (int m = 0; m < NMK; ++m) v += xmark[row*NMK + m] * temp_w[m*DM + o];
  int i = o >> 1;
  float ang = (float)l * expf((float)(2*i) * -0.07195578415606394f); // -ln(10000)/128
  v += (o & 1) ? cosf(ang) : sinf(ang);
  xbuf[row*DM + o] = v;
}

// ---------------- 3. in_proj GEMM 64x64 tile; epilogue splits xi / silu(z) ----------------
template<int MODE>
__global__ __launch_bounds__(256) void gemm64_kernel(const float* __restrict__ A,
    const float* __restrict__ W, float* __restrict__ out0, float* __restrict__ out1,
    int M, int N, int K){
  __shared__ float AsT[32][68];
  __shared__ float Bs[32][64];
  int tid = threadIdx.x;
  int tx = tid & 15, ty = tid >> 4;
  int rowBase = blockIdx.x * 64, colBase = blockIdx.y * 64;
  float acc[4][4] = {};
  for (int kc = 0; kc < K; kc += 32){
    #pragma unroll
    for (int i = 0; i < 8; ++i){
      int idx = tid + i*256;
      int r = idx >> 5, k = idx & 31;
      AsT[k][r] = A[(size_t)(rowBase + r)*K + kc + k];
    }
    #pragma unroll
    for (int i = 0; i < 8; ++i){
      int idx = tid + i*256;
      int k = idx >> 6, c = idx & 63;
      Bs[k][c] = W[(size_t)(kc + k)*N + colBase + c];
    }
    __syncthreads();
    #pragma unroll
    for (int k = 0; k < 32; ++k){
      float4 a  = *(const float4*)&AsT[k][ty*4];
      float4 bv = *(const float4*)&Bs[k][tx*4];
      float av[4] = {a.x, a.y, a.z, a.w};
      float bb[4] = {bv.x, bv.y, bv.z, bv.w};
      #pragma unroll
      for (int ii = 0; ii < 4; ++ii)
        #pragma unroll
        for (int jj = 0; jj < 4; ++jj) acc[ii][jj] += av[ii]*bb[jj];
    }
    __syncthreads();
  }
  #pragma unroll
  for (int ii = 0; ii < 4; ++ii){
    int row = rowBase + ty*4 + ii;
    #pragma unroll
    for (int jj = 0; jj < 4; ++jj){
      int col = colBase + tx*4 + jj;
      float v = acc[ii][jj];
      if (MODE == 0){
        out0[(size_t)row*N + col] = v;
      } else {
        if (col < DI) out0[(size_t)row*DI + col] = v;
        else          out1[(size_t)row*DI + col - DI] = silu_f(v);
      }
    }
  }
}

// ---------------- 4. depthwise causal conv + silu ----------------
__global__ void conv_kernel(const float* __restrict__ xi_raw, const float* __restrict__ conv_w,
                            const float* __restrict__ conv_b, float* __restrict__ xi2){
  int row = blockIdx.x, d = threadIdx.x;
  int l = row & 511;
  float acc = conv_b[d];
  #pragma unroll
  for (int k = 0; k < 4; ++k){
    int t = l + k - 3;
    if (t >= 0) acc += xi_raw[(size_t)(row + k - 3)*DI + d] * conv_w[d*4 + k];
  }
  xi2[(size_t)row*DI + d] = silu_f(acc);
}

// ---------------- 5. dbl GEMM (N=40) + fused dt projection/softplus ----------------
// 32-row tiles -> 512 blocks (2/CU). 256 thr = 32 rows x 8 colgroups of 6 (N pad 48).
__global__ __launch_bounds__(256) void dbl_kernel(const float* __restrict__ xi2,
    const float* __restrict__ xpw, const float* __restrict__ dt_w,
    const float* __restrict__ dt_b, float* __restrict__ Bpack,
    float* __restrict__ Cpack, float* __restrict__ dtpre){
  __shared__ float Xs[64][33];    // [k][row]
  __shared__ float Ws[64][48];    // [k][col], 40 padded to 48
  __shared__ float rowp8[32][8];
  int t = threadIdx.x;
  int r = t >> 3, g = t & 7;      // row 0..31, colgroup 0..7 (6 cols each)
  int rowBase = blockIdx.x * 32;
  float acc[6] = {};
  for (int kc = 0; kc < DI; kc += 64){
    #pragma unroll
    for (int i = 0; i < 8; ++i){
      int idx = t + i*256;
      int rr = idx >> 6, k = idx & 63;
      Xs[k][rr] = xi2[(size_t)(rowBase + rr)*DI + kc + k];
    }
    #pragma unroll
    for (int i = 0; i < 12; ++i){
      int idx = t + i*256;
      int k = idx / 48, j = idx % 48;
      Ws[k][j] = (j < 40) ? xpw[(kc + k)*40 + j] : 0.f;
    }
    __syncthreads();
    #pragma unroll 8
    for (int k = 0; k < 64; ++k){
      float a = Xs[k][r];
      const float2* wr = (const float2*)&Ws[k][g*6];
      float2 w0 = wr[0], w1 = wr[1], w2 = wr[2];
      acc[0] += a*w0.x; acc[1] += a*w0.y;
      acc[2] += a*w1.x; acc[3] += a*w1.y;
      acc[4] += a*w2.x; acc[5] += a*w2.y;
    }
    __syncthreads();
  }
  size_t row = rowBase + r;
  #pragma unroll
  for (int jj = 0; jj < 6; ++jj){
    int j = g*6 + jj;
    if (j < 8)             rowp8[r][j] = acc[jj];
    else if (j < 24)       Bpack[row*16 + (j - 8)]  = acc[jj];
    else if (j < 40)       Cpack[row*16 + (j - 24)] = acc[jj];
  }
  __syncthreads();
  // dt phase: thread t = channel d; 32 rows each
  float dtw_l[8];
  #pragma unroll
  for (int q = 0; q < 8; ++q) dtw_l[q] = dt_w[q*DI + t];
  float dtb_l = dt_b[t];
  for (int rr = 0; rr < 32; ++rr){
    float dtp = dtb_l;
    #pragma unroll
    for (int q = 0; q < 8; ++q) dtp += rowp8[rr][q] * dtw_l[q];
    float dt = fmaxf(dtp, 0.f) + log1pf(__expf(-fabsf(dtp)));
    dtpre[(size_t)(rowBase + rr)*DI + t] = dt;
  }
}

// ---------------- 6a. chunk-local scan (pipelined, native exp) ----------------
__global__ __launch_bounds__(256) void scan_part1_kernel(const float* __restrict__ dtpre,
    const float* __restrict__ xi2, const float* __restrict__ Bpack,
    const float* __restrict__ A_log, float* __restrict__ hend, float* __restrict__ Pprod){
  int t = threadIdx.x;
  int n = t & 15, dl = t >> 4;
  int d = blockIdx.y * 16 + dl;
  int b = blockIdx.x, j = blockIdx.z;
  float A = -__expf(A_log[d*DSN + n]);
  float h = 0.f, dtsum = 0.f;
  const size_t row0 = (size_t)b * LL + (size_t)j * CL;
  const float* pdt = dtpre + row0*DI + d;
  const float* pB  = Bpack + row0*DSN + n;
  const float* pxi = xi2   + row0*DI + d;

  float dtA[4], BvA[4], xiA[4];
  float dtB[4], BvB[4], xiB[4];
  #pragma unroll
  for (int i = 0; i < 4; ++i){ dtA[i]=pdt[i*DI]; BvA[i]=pB[i*DSN]; xiA[i]=pxi[i*DI]; }
  pdt += 4*DI; pB += 4*DSN; pxi += 4*DI;
  #pragma unroll
  for (int g = 0; g < CL/8; ++g){
    #pragma unroll
    for (int i = 0; i < 4; ++i){ dtB[i]=pdt[i*DI]; BvB[i]=pB[i*DSN]; xiB[i]=pxi[i*DI]; }
    pdt += 4*DI; pB += 4*DSN; pxi += 4*DI;
    #pragma unroll
    for (int i = 0; i < 4; ++i){
      float dA = __expf(dtA[i]*A);
      h = dA*h + (dtA[i]*xiA[i])*BvA[i];
      dtsum += dtA[i];
    }
    if (g < CL/8 - 1){
      #pragma unroll
      for (int i = 0; i < 4; ++i){ dtA[i]=pdt[i*DI]; BvA[i]=pB[i*DSN]; xiA[i]=pxi[i*DI]; }
      pdt += 4*DI; pB += 4*DSN; pxi += 4*DI;
    }
    #pragma unroll
    for (int i = 0; i < 4; ++i){
      float dA = __expf(dtB[i]*A);
      h = dA*h + (dtB[i]*xiB[i])*BvB[i];
      dtsum += dtB[i];
    }
  }
  size_t idx = (((size_t)b*DI + d)*DSN + n)*NC + j;
  hend[idx]  = h;
  Pprod[idx] = __expf(A * dtsum);
}

// ---------------- 6b. final scan per chunk, carry computed inline ----------------
__global__ __launch_bounds__(256) void scan_part2_kernel(const float* __restrict__ dtpre,
    const float* __restrict__ xi2, const float* __restrict__ zbuf,
    const float* __restrict__ Bpack, const float* __restrict__ Cpack,
    const float* __restrict__ A_log, const float* __restrict__ Dp,
    const float* __restrict__ hend, const float* __restrict__ Pprod,
    float* __restrict__ ybuf){
  int t = threadIdx.x;
  int n = t & 15, dl = t >> 4;
  int d = blockIdx.y * 16 + dl;
  int b = blockIdx.x, j = blockIdx.z;
  float A = -__expf(A_log[d*DSN + n]);
  float Dd = Dp[d];
  // inline carry over previous chunks
  size_t cb = (((size_t)b*DI + d)*DSN + n)*NC;
  float h = 0.f;
  for (int jj = 0; jj < j; ++jj) h = Pprod[cb + jj]*h + hend[cb + jj];

  const size_t row0 = (size_t)b * LL + (size_t)j * CL;
  const float* pdt = dtpre + row0*DI + d;
  const float* pB  = Bpack + row0*DSN + n;
  const float* pC  = Cpack + row0*DSN + n;
  const float* pxi = xi2   + row0*DI + d;
  const float* pz  = zbuf  + row0*DI + d;
  float* py = ybuf + row0*DI + d;

  float dtA[4], BvA[4], CvA[4], xiA[4], zA[4];
  float dtB[4], BvB[4], CvB[4], xiB[4], zB[4];
  #pragma unroll
  for (int i = 0; i < 4; ++i){
    dtA[i]=pdt[i*DI]; BvA[i]=pB[i*DSN]; CvA[i]=pC[i*DSN]; xiA[i]=pxi[i*DI]; zA[i]=pz[i*DI];
  }
  pdt += 4*DI; pB += 4*DSN; pC += 4*DSN; pxi += 4*DI; pz += 4*DI;
  #pragma unroll
  for (int g = 0; g < CL/8; ++g){
    #pragma unroll
    for (int i = 0; i < 4; ++i){
      dtB[i]=pdt[i*DI]; BvB[i]=pB[i*DSN]; CvB[i]=pC[i*DSN]; xiB[i]=pxi[i*DI]; zB[i]=pz[i*DI];
    }
    pdt += 4*DI; pB += 4*DSN; pC += 4*DSN; pxi += 4*DI; pz += 4*DI;
    #pragma unroll
    for (int i = 0; i < 4; ++i){
      float dA = __expf(dtA[i]*A);
      h = dA*h + (dtA[i]*xiA[i])*BvA[i];
      float p = h * CvA[i];
      p += __shfl_xor(p, 8, 16);
      p += __shfl_xor(p, 4, 16);
      p += __shfl_xor(p, 2, 16);
      p += __shfl_xor(p, 1, 16);
      if (n == 0) py[i*DI] = (p + Dd*xiA[i]) * zA[i];
    }
    py += 4*DI;
    if (g < CL/8 - 1){
      #pragma unroll
      for (int i = 0; i < 4; ++i){
        dtA[i]=pdt[i*DI]; BvA[i]=pB[i*DSN]; CvA[i]=pC[i*DSN]; xiA[i]=pxi[i*DI]; zA[i]=pz[i*DI];
      }
      pdt += 4*DI; pB += 4*DSN; pC += 4*DSN; pxi += 4*DI; pz += 4*DI;
    }
    #pragma unroll
    for (int i = 0; i < 4; ++i){
      float dA = __expf(dtB[i]*A);
      h = dA*h + (dtB[i]*xiB[i])*BvB[i];
      float p = h * CvB[i];
      p += __shfl_xor(p, 8, 16);
      p += __shfl_xor(p, 4, 16);
      p += __shfl_xor(p, 2, 16);
      p += __shfl_xor(p, 1, 16);
      if (n == 0) py[i*DI] = (p + Dd*xiB[i]) * zB[i];
    }
    py += 4*DI;
  }
}

// ---------------- 7. out_proj GEMM (64x128 tile) + fused outlayer/denorm/fc0 ----------------
__global__ __launch_bounds__(256) void gemm_out_kernel(const float* __restrict__ A,
    const float* __restrict__ W, const float* __restrict__ olw,
    const float* __restrict__ stats, const float* __restrict__ fc0w,
    const float* __restrict__ fc0b, float* __restrict__ h0){
  __shared__ float AsT[32][68];
  __shared__ float Bs[32][128];
  int tid = threadIdx.x;
  int tx = tid & 15, ty = tid >> 4;
  int rowBase = blockIdx.x * 64;
  float acc[4][8] = {};
  for (int kc = 0; kc < DI; kc += 32){
    #pragma unroll
    for (int i = 0; i < 8; ++i){
      int idx = tid + i*256;
      int r = idx >> 5, k = idx & 31;
      AsT[k][r] = A[(size_t)(rowBase + r)*DI + kc + k];
    }
    #pragma unroll
    for (int i = 0; i < 16; ++i){
      int idx = tid + i*256;
      int k = idx >> 7, c = idx & 127;
      Bs[k][c] = W[(size_t)(kc + k)*DM + c];
    }
    __syncthreads();
    #pragma unroll
    for (int k = 0; k < 32; ++k){
      float4 a  = *(const float4*)&AsT[k][ty*4];
      float4 b0 = *(const float4*)&Bs[k][tx*4];
      float4 b1 = *(const float4*)&Bs[k][64 + tx*4];
      float av[4] = {a.x, a.y, a.z, a.w};
      float b0v[4] = {b0.x, b0.y, b0.z, b0.w};
      float b1v[4] = {b1.x, b1.y, b1.z, b1.w};
      #pragma unroll
      for (int ii = 0; ii < 4; ++ii){
        #pragma unroll
        for (int jj = 0; jj < 4; ++jj){
          acc[ii][jj]     += av[ii]*b0v[jj];
          acc[ii][jj + 4] += av[ii]*b1v[jj];
        }
      }
    }
    __syncthreads();
  }
  float w0[4], w1[4];
  #pragma unroll
  for (int q = 0; q < 4; ++q){ w0[q] = olw[tx*4 + q]; w1[q] = olw[64 + tx*4 + q]; }
  int b = rowBase >> 9;
  float mean = stats[b], sd = stats[BB + b];
  float f0w = fc0w[0], f0b = fc0b[0];
  #pragma unroll
  for (int ii = 0; ii < 4; ++ii){
    float s = 0.f;
    #pragma unroll
    for (int q = 0; q < 4; ++q) s += acc[ii][q]*w0[q] + acc[ii][q + 4]*w1[q];
    s += __shfl_xor(s, 8, 16);
    s += __shfl_xor(s, 4, 16);
    s += __shfl_xor(s, 2, 16);
    s += __shfl_xor(s, 1, 16);
    if (tx == 0){
      float xo = s*sd + mean;
      float dec = fmaxf(xo, 0.f);
      h0[rowBase + ty*4 + ii] = fmaxf(dec*f0w + f0b, 0.f);
    }
  }
}

// ---------------- 9. final MLP per batch ----------------
__global__ __launch_bounds__(128) void mlp_kernel(const float* __restrict__ h0,
    const float* __restrict__ fc1w, const float* __restrict__ fc1b,
    const float* __restrict__ fc2w, const float* __restrict__ fc2b,
    const float* __restrict__ fc3w, const float* __restrict__ fc3b,
    float* __restrict__ out){
  __shared__ float h0s[LL];
  __shared__ float h1s[128];
  __shared__ float h2s[64];
  int b = blockIdx.x, t = threadIdx.x;
  #pragma unroll
  for (int i = 0; i < 4; ++i) h0s[t + i*128] = h0[b*LL + t + i*128];
  __syncthreads();
  float a = fc1b[t];
  for (int l = 0; l < LL; ++l) a += h0s[l] * fc1w[l*128 + t];
  h1s[t] = fmaxf(a, 0.f);
  __syncthreads();
  if (t < 64){
    float a2 = fc2b[t];
    #pragma unroll 4
    for (int k = 0; k < 128; ++k) a2 += h1s[k] * fc2w[k*64 + t];
    h2s[t] = fmaxf(a2, 0.f);
  }
  __syncthreads();
  if (t < 64){
    float p = h2s[t] * fc3w[t];
    #pragma unroll
    for (int off = 32; off; off >>= 1) p += __shfl_down(p, off);
    if (t == 0) out[b] = p + fc3b[0];
  }
}

extern "C" void kernel_launch(void* const* d_in, const int* in_sizes, int n_in,
                              void* d_out, int out_size, void* d_ws, size_t ws_size,
                              hipStream_t stream){
  const float* x_enc      = (const float*)d_in[0];
  const float* x_mark_enc = (const float*)d_in[1];
  const float* tok_w      = (const float*)d_in[4];
  const float* temp_w     = (const float*)d_in[5];
  const float* in_proj_w  = (const float*)d_in[6];
  const float* conv_w     = (const float*)d_in[7];
  const float* conv_b     = (const float*)d_in[8];
  const float* x_proj_w   = (const float*)d_in[9];
  const float* dt_w       = (const float*)d_in[10];
  const float* dt_b       = (const float*)d_in[11];
  const float* A_log      = (const float*)d_in[12];
  const float* Dp         = (const float*)d_in[13];
  const float* out_proj_w = (const float*)d_in[14];
  const float* out_lay_w  = (const float*)d_in[15];
  const float* fc0_w      = (const float*)d_in[16];
  const float* fc0_b      = (const float*)d_in[17];
  const float* fc1_w      = (const float*)d_in[18];
  const float* fc1_b      = (const float*)d_in[19];
  const float* fc2_w      = (const float*)d_in[20];
  const float* fc2_b      = (const float*)d_in[21];
  const float* fc3_w      = (const float*)d_in[22];
  const float* fc3_b      = (const float*)d_in[23];
  float* outp = (float*)d_out;

  float* ws = (float*)d_ws;
  const int M = BB*LL;
  float* xn     = ws;                                   // M
  float* stats  = xn + M;                               // 64
  float* xbuf   = stats + 64;                           // M*128 (8MB)
  float* xi_raw = xbuf + (size_t)M*DM;                  // M*256
  float* zbuf   = xi_raw + (size_t)M*DI;                // M*256
  float* xi2    = zbuf + (size_t)M*DI;                  // M*256
  float* Bpack  = xi2 + (size_t)M*DI;                   // M*16
  float* Cpack  = Bpack + (size_t)M*16;                 // M*16
  float* dtpre  = Cpack + (size_t)M*16;                 // M*256
  float* h0     = dtpre + (size_t)M*DI;                 // M
  float* ybuf   = xi_raw;                               // reuse (dead after conv)
  // hend/Pprod live in xbuf (dead after in_proj gemm)
  float* hend   = xbuf;
  float* Pprod  = xbuf + (size_t)BB*DI*DSN*NC;

  norm_kernel<<<BB, 256, 0, stream>>>(x_enc, xn, stats);
  embed_kernel<<<M, DM, 0, stream>>>(xn, x_mark_enc, tok_w, temp_w, xbuf);
  gemm64_kernel<1><<<dim3(M/64, 8), 256, 0, stream>>>(xbuf, in_proj_w, xi_raw, zbuf, M, 512, DM);
  conv_kernel<<<M, DI, 0, stream>>>(xi_raw, conv_w, conv_b, xi2);
  dbl_kernel<<<M/32, 256, 0, stream>>>(xi2, x_proj_w, dt_w, dt_b, Bpack, Cpack, dtpre);
  scan_part1_kernel<<<dim3(BB, DI/16, NC), 256, 0, stream>>>(dtpre, xi2, Bpack, A_log, hend, Pprod);
  scan_part2_kernel<<<dim3(BB, DI/16, NC), 256, 0, stream>>>(dtpre, xi2, zbuf, Bpack, Cpack, A_log, Dp, hend, Pprod, ybuf);
  gemm_out_kernel<<<M/64, 256, 0, stream>>>(ybuf, out_proj_w, out_lay_w, stats, fc0_w, fc0_b, h0);
  mlp_kernel<<<BB, 128, 0, stream>>>(h0, fc1_w, fc1_b, fc2_w, fc2_b, fc3_w, fc3_b, outp);
}